// Round 1
// baseline (2320.053 us; speedup 1.0000x reference)
//
#include <hip/hip_runtime.h>

// GCN 2-layer: h = relu(Anorm @ (emb[x] @ W1) + b1); out = relu(Anorm @ (h @ W2) + b2)
// Anorm = D^-1/2 (A+I) D^-1/2, self-loops folded into epilogue as dinv[i]^2 * hw[i].

#define NDIM 128  // embed == hidden == 128

__global__ void degree_count(const int* __restrict__ dst, float* __restrict__ deg, int E) {
    int e = blockIdx.x * blockDim.x + threadIdx.x;
    if (e < E) atomicAdd(&deg[dst[e]], 1.0f);
}

__global__ void finalize_dinv(float* __restrict__ deg, int n) {
    int i = blockIdx.x * blockDim.x + threadIdx.x;
    if (i < n) deg[i] = rsqrtf(deg[i] + 1.0f);  // +1 for self-loop
}

// out[r][:] = H[idx ? idx[r] : r][:] @ W   (K = 128)
// block = 256 threads, tile = 64 rows x 64 cols (gridDim.y = 2 covers 128 cols)
// per-thread 4x4 register tile; sHT stored transposed so both operands are b128.
__global__ __launch_bounds__(256, 2)
void gemm128(const float* __restrict__ H, const int* __restrict__ idx,
             const float* __restrict__ W, float* __restrict__ out, int n) {
    __shared__ float sHT[128 * 64];  // [k][r], 32 KB
    __shared__ float sW[128 * 64];   // [k][j], 32 KB
    const int tid = threadIdx.x;
    const int rbase = blockIdx.x * 64;
    const int jhalf = blockIdx.y * 64;

    // stage W column-half: 128k x 64j = 2048 float4
    {
        const float4* W4 = (const float4*)W;  // W row = 32 float4
        float4* sW4 = (float4*)sW;
        const int jh4 = jhalf >> 2;
#pragma unroll
        for (int i = 0; i < 8; ++i) {
            int c = tid + i * 256;
            int k = c >> 4, jc = c & 15;
            sW4[c] = W4[k * 32 + jh4 + jc];
        }
    }
    // stage 64 H rows transposed: lane r = tid&63 owns row r -> conflict-free LDS stores
    {
        const int r = tid & 63;
        const int gr = rbase + r;
        const int src_row = (gr < n) ? (idx ? idx[gr] : gr) : 0;
        const float4* H4 = (const float4*)H;  // H row = 32 float4
        const int kc0 = tid >> 6;
#pragma unroll
        for (int i = 0; i < 8; ++i) {
            int kc = kc0 + (i << 2);  // 0..31
            float4 v = H4[(size_t)src_row * 32 + kc];
            int k = kc << 2;
            sHT[(k + 0) * 64 + r] = v.x;
            sHT[(k + 1) * 64 + r] = v.y;
            sHT[(k + 2) * 64 + r] = v.z;
            sHT[(k + 3) * 64 + r] = v.w;
        }
    }
    __syncthreads();

    const int jt = (tid & 15) << 2;  // col offset within 64
    const int rt = (tid >> 4) << 2;  // row offset within 64
    float acc[4][4] = {};
#pragma unroll 4
    for (int k = 0; k < 128; ++k) {
        float4 a = *(const float4*)&sHT[k * 64 + rt];
        float4 b = *(const float4*)&sW[k * 64 + jt];
        acc[0][0] = fmaf(a.x, b.x, acc[0][0]); acc[0][1] = fmaf(a.x, b.y, acc[0][1]);
        acc[0][2] = fmaf(a.x, b.z, acc[0][2]); acc[0][3] = fmaf(a.x, b.w, acc[0][3]);
        acc[1][0] = fmaf(a.y, b.x, acc[1][0]); acc[1][1] = fmaf(a.y, b.y, acc[1][1]);
        acc[1][2] = fmaf(a.y, b.z, acc[1][2]); acc[1][3] = fmaf(a.y, b.w, acc[1][3]);
        acc[2][0] = fmaf(a.z, b.x, acc[2][0]); acc[2][1] = fmaf(a.z, b.y, acc[2][1]);
        acc[2][2] = fmaf(a.z, b.z, acc[2][2]); acc[2][3] = fmaf(a.z, b.w, acc[2][3]);
        acc[3][0] = fmaf(a.w, b.x, acc[3][0]); acc[3][1] = fmaf(a.w, b.y, acc[3][1]);
        acc[3][2] = fmaf(a.w, b.z, acc[3][2]); acc[3][3] = fmaf(a.w, b.w, acc[3][3]);
    }

#pragma unroll
    for (int q = 0; q < 4; ++q) {
        int gr = rbase + rt + q;
        if (gr < n) {
            float4 o = make_float4(acc[q][0], acc[q][1], acc[q][2], acc[q][3]);
            *(float4*)&out[(size_t)gr * NDIM + jhalf + jt] = o;
        }
    }
}

// agg[dst] += dinv[src]*dinv[dst] * hw[src]; 32 lanes per edge, float4/lane
__global__ void aggregate(const float* __restrict__ hw, const int* __restrict__ src,
                          const int* __restrict__ dst, const float* __restrict__ dinv,
                          float* __restrict__ agg, int E) {
    int t = blockIdx.x * blockDim.x + threadIdx.x;
    int e = t >> 5;
    if (e >= E) return;
    int lane = t & 31;
    int s = src[e], d = dst[e];
    float norm = dinv[s] * dinv[d];
    float4 v = ((const float4*)hw)[(size_t)s * 32 + lane];
    float* o = agg + (size_t)d * NDIM + lane * 4;
    atomicAdd(o + 0, norm * v.x);
    atomicAdd(o + 1, norm * v.y);
    atomicAdd(o + 2, norm * v.z);
    atomicAdd(o + 3, norm * v.w);
}

// hio = relu(agg + dinv^2 * hio + bias)   (in place on hio)
__global__ void epilogue(const float* __restrict__ agg, float* __restrict__ hio,
                         const float* __restrict__ dinv, const float* __restrict__ bias,
                         int n) {
    int t = blockIdx.x * blockDim.x + threadIdx.x;
    int i = t >> 5, c = t & 31;
    if (i >= n) return;
    float di = dinv[i];
    float self = di * di;
    size_t off = (size_t)i * 32 + c;
    float4 a = ((const float4*)agg)[off];
    float4 h = ((float4*)hio)[off];
    float4 b = ((const float4*)bias)[c];
    float4 o;
    o.x = fmaxf(fmaf(self, h.x, a.x) + b.x, 0.0f);
    o.y = fmaxf(fmaf(self, h.y, a.y) + b.y, 0.0f);
    o.z = fmaxf(fmaf(self, h.z, a.z) + b.z, 0.0f);
    o.w = fmaxf(fmaf(self, h.w, a.w) + b.w, 0.0f);
    ((float4*)hio)[off] = o;
}

extern "C" void kernel_launch(void* const* d_in, const int* in_sizes, int n_in,
                              void* d_out, int out_size, void* d_ws, size_t ws_size,
                              hipStream_t stream) {
    const int* x = (const int*)d_in[0];
    const int* edge_index = (const int*)d_in[1];
    const float* emb = (const float*)d_in[2];
    const float* W1 = (const float*)d_in[3];
    const float* b1 = (const float*)d_in[4];
    const float* W2 = (const float*)d_in[5];
    const float* b2 = (const float*)d_in[6];
    float* out = (float*)d_out;

    const int N = in_sizes[0];
    const int E = in_sizes[1] / 2;
    const int* src = edge_index;
    const int* dst = edge_index + E;

    // workspace: dinv [N floats] | bufA [N*128 floats]
    float* dinv = (float*)d_ws;
    size_t dinv_bytes = ((size_t)N * sizeof(float) + 511) & ~(size_t)511;
    float* bufA = (float*)((char*)d_ws + dinv_bytes);
    const size_t feat_bytes = (size_t)N * NDIM * sizeof(float);

    // degrees -> dinv
    hipMemsetAsync(dinv, 0, (size_t)N * sizeof(float), stream);
    degree_count<<<(E + 255) / 256, 256, 0, stream>>>(dst, dinv, E);
    finalize_dinv<<<(N + 255) / 256, 256, 0, stream>>>(dinv, N);

    dim3 ggrid((N + 63) / 64, 2);

    // layer 1: hw1 = emb[x] @ W1 -> bufA ; agg1 -> d_out ; h1 = relu(...) in bufA
    gemm128<<<ggrid, 256, 0, stream>>>(emb, x, W1, bufA, N);
    hipMemsetAsync(out, 0, feat_bytes, stream);
    aggregate<<<(E * 32 + 255) / 256, 256, 0, stream>>>(bufA, src, dst, dinv, out, E);
    epilogue<<<((size_t)N * 32 + 255) / 256, 256, 0, stream>>>(out, bufA, dinv, b1, N);

    // layer 2: hw2 = h1 @ W2 -> d_out ; agg2 -> bufA ; out = relu(...) in d_out
    gemm128<<<ggrid, 256, 0, stream>>>(bufA, nullptr, W2, out, N);
    hipMemsetAsync(bufA, 0, feat_bytes, stream);
    aggregate<<<(E * 32 + 255) / 256, 256, 0, stream>>>(out, src, dst, dinv, bufA, E);
    epilogue<<<((size_t)N * 32 + 255) / 256, 256, 0, stream>>>(bufA, out, dinv, b2, N);
}

// Round 2
// 382.927 us; speedup vs baseline: 6.0587x; 6.0587x over previous
//
#include <hip/hip_runtime.h>

// GCN 2-layer: h1 = relu(Anorm @ (emb[x] @ W1) + b1); out = relu(Anorm @ (h1 @ W2) + b2)
// Anorm = D^-1/2 (A+I) D^-1/2. Self-loop folded into aggregation as dinv[i]^2 * hw[i].
// Atomic-free aggregation via on-device CSR build (count -> scan -> scatter).

#define NDIM 128
#define SCAN_IPT 4
#define SCAN_BLK 256
#define SCAN_IPB (SCAN_BLK * SCAN_IPT)  // 1024 elements per scan block

__global__ void degree_count(const int* __restrict__ dst, int* __restrict__ cnt, int E) {
    int e = blockIdx.x * blockDim.x + threadIdx.x;
    if (e < E) atomicAdd(&cnt[dst[e]], 1);
}

__global__ void finalize_dinv(const int* __restrict__ cnt, float* __restrict__ dinv, int n) {
    int i = blockIdx.x * blockDim.x + threadIdx.x;
    if (i < n) dinv[i] = rsqrtf((float)cnt[i] + 1.0f);  // +1 self-loop
}

// ---- 3-kernel exclusive scan of cnt[0..n) -> rp[0..n) ----
__global__ void scan_blocks(const int* __restrict__ in, int* __restrict__ out,
                            int* __restrict__ bsums, int n) {
    __shared__ int lds[SCAN_BLK];
    const int t = threadIdx.x;
    const int base = blockIdx.x * SCAN_IPB + t * SCAN_IPT;
    int v[SCAN_IPT];
    int s = 0;
#pragma unroll
    for (int k = 0; k < SCAN_IPT; ++k) { v[k] = (base + k < n) ? in[base + k] : 0; s += v[k]; }
    lds[t] = s;
    __syncthreads();
    for (int off = 1; off < SCAN_BLK; off <<= 1) {  // Hillis-Steele inclusive
        int x = (t >= off) ? lds[t - off] : 0;
        __syncthreads();
        lds[t] += x;
        __syncthreads();
    }
    if (t == SCAN_BLK - 1) bsums[blockIdx.x] = lds[t];
    int run = (t == 0) ? 0 : lds[t - 1];
#pragma unroll
    for (int k = 0; k < SCAN_IPT; ++k) {
        if (base + k < n) out[base + k] = run;
        run += v[k];
    }
}

__global__ void scan_partials(int* __restrict__ bsums, int nb) {
    __shared__ int lds[128];
    const int t = threadIdx.x;
    lds[t] = (t < nb) ? bsums[t] : 0;
    __syncthreads();
    for (int off = 1; off < 128; off <<= 1) {
        int x = (t >= off) ? lds[t - off] : 0;
        __syncthreads();
        lds[t] += x;
        __syncthreads();
    }
    if (t < nb) bsums[t] = (t == 0) ? 0 : lds[t - 1];  // exclusive
}

__global__ void add_offsets(int* __restrict__ rp, const int* __restrict__ bsums, int n, int E) {
    int i = blockIdx.x * blockDim.x + threadIdx.x;
    if (i < n) rp[i] += bsums[i / SCAN_IPB];
    if (i == 0) rp[n] = E;
}

__global__ void fill_edges(const int* __restrict__ src, const int* __restrict__ dst,
                           const int* __restrict__ rp, int* __restrict__ cur,
                           int* __restrict__ esrc, int E) {
    int e = blockIdx.x * blockDim.x + threadIdx.x;
    if (e >= E) return;
    int d = dst[e];
    int p = rp[d] + atomicAdd(&cur[d], 1);
    esrc[p] = src[e];
}

// ---- GEMM: out[r][:] = H[idx ? idx[r] : r][:] @ W  (K=128) ----
// 256 threads, 64 rows x 64 cols per block (gridDim.y=2), 4x4 register tile.
__global__ __launch_bounds__(256, 2)
void gemm128(const float* __restrict__ H, const int* __restrict__ idx,
             const float* __restrict__ W, float* __restrict__ out, int n) {
    __shared__ float sHT[128 * 64];  // [k][r]
    __shared__ float sW[128 * 64];   // [k][j]
    const int tid = threadIdx.x;
    const int rbase = blockIdx.x * 64;
    const int jhalf = blockIdx.y * 64;

    {
        const float4* W4 = (const float4*)W;
        float4* sW4 = (float4*)sW;
        const int jh4 = jhalf >> 2;
#pragma unroll
        for (int i = 0; i < 8; ++i) {
            int c = tid + i * 256;
            int k = c >> 4, jc = c & 15;
            sW4[c] = W4[k * 32 + jh4 + jc];
        }
    }
    {
        const int r = tid & 63;
        const int gr = rbase + r;
        const int src_row = (gr < n) ? (idx ? idx[gr] : gr) : 0;
        const float4* H4 = (const float4*)H;
        const int kc0 = tid >> 6;
#pragma unroll
        for (int i = 0; i < 8; ++i) {
            int kc = kc0 + (i << 2);
            float4 v = H4[(size_t)src_row * 32 + kc];
            int k = kc << 2;
            sHT[(k + 0) * 64 + r] = v.x;
            sHT[(k + 1) * 64 + r] = v.y;
            sHT[(k + 2) * 64 + r] = v.z;
            sHT[(k + 3) * 64 + r] = v.w;
        }
    }
    __syncthreads();

    const int jt = (tid & 15) << 2;
    const int rt = (tid >> 4) << 2;
    float acc[4][4] = {};
#pragma unroll 4
    for (int k = 0; k < 128; ++k) {
        float4 a = *(const float4*)&sHT[k * 64 + rt];
        float4 b = *(const float4*)&sW[k * 64 + jt];
        acc[0][0] = fmaf(a.x, b.x, acc[0][0]); acc[0][1] = fmaf(a.x, b.y, acc[0][1]);
        acc[0][2] = fmaf(a.x, b.z, acc[0][2]); acc[0][3] = fmaf(a.x, b.w, acc[0][3]);
        acc[1][0] = fmaf(a.y, b.x, acc[1][0]); acc[1][1] = fmaf(a.y, b.y, acc[1][1]);
        acc[1][2] = fmaf(a.y, b.z, acc[1][2]); acc[1][3] = fmaf(a.y, b.w, acc[1][3]);
        acc[2][0] = fmaf(a.z, b.x, acc[2][0]); acc[2][1] = fmaf(a.z, b.y, acc[2][1]);
        acc[2][2] = fmaf(a.z, b.z, acc[2][2]); acc[2][3] = fmaf(a.z, b.w, acc[2][3]);
        acc[3][0] = fmaf(a.w, b.x, acc[3][0]); acc[3][1] = fmaf(a.w, b.y, acc[3][1]);
        acc[3][2] = fmaf(a.w, b.z, acc[3][2]); acc[3][3] = fmaf(a.w, b.w, acc[3][3]);
    }

#pragma unroll
    for (int q = 0; q < 4; ++q) {
        int gr = rbase + rt + q;
        if (gr < n) {
            float4 o = make_float4(acc[q][0], acc[q][1], acc[q][2], acc[q][3]);
            *(float4*)&out[(size_t)gr * NDIM + jhalf + jt] = o;
        }
    }
}

// ---- Aggregation: 32-lane group per dst row, register accumulate, fused self+bias+relu ----
__global__ void aggregate_csr(const float* __restrict__ hw, const int* __restrict__ rp,
                              const int* __restrict__ esrc, const float* __restrict__ dinv,
                              const float* __restrict__ bias, float* __restrict__ out, int n) {
    int t = blockIdx.x * blockDim.x + threadIdx.x;
    int i = t >> 5, lane = t & 31;
    if (i >= n) return;
    const float4* hw4 = (const float4*)hw;
    float di = dinv[i];
    float4 h = hw4[(size_t)i * 32 + lane];
    float self = di * di;
    float4 acc = make_float4(self * h.x, self * h.y, self * h.z, self * h.w);
    int beg = rp[i], end = rp[i + 1];
    for (int j = beg; j < end; ++j) {
        int s = esrc[j];
        float nm = di * dinv[s];
        float4 v = hw4[(size_t)s * 32 + lane];
        acc.x = fmaf(nm, v.x, acc.x);
        acc.y = fmaf(nm, v.y, acc.y);
        acc.z = fmaf(nm, v.z, acc.z);
        acc.w = fmaf(nm, v.w, acc.w);
    }
    float4 b = ((const float4*)bias)[lane];
    acc.x = fmaxf(acc.x + b.x, 0.0f);
    acc.y = fmaxf(acc.y + b.y, 0.0f);
    acc.z = fmaxf(acc.z + b.z, 0.0f);
    acc.w = fmaxf(acc.w + b.w, 0.0f);
    ((float4*)out)[(size_t)i * 32 + lane] = acc;
}

extern "C" void kernel_launch(void* const* d_in, const int* in_sizes, int n_in,
                              void* d_out, int out_size, void* d_ws, size_t ws_size,
                              hipStream_t stream) {
    const int* x = (const int*)d_in[0];
    const int* edge_index = (const int*)d_in[1];
    const float* emb = (const float*)d_in[2];
    const float* W1 = (const float*)d_in[3];
    const float* b1 = (const float*)d_in[4];
    const float* W2 = (const float*)d_in[5];
    const float* b2 = (const float*)d_in[6];
    float* out = (float*)d_out;

    const int N = in_sizes[0];
    const int E = in_sizes[1] / 2;
    const int* src = edge_index;
    const int* dst = edge_index + E;

    // workspace layout (512B-aligned chunks):
    // cnt[N] | cur[N] (contiguous with cnt for one memset) | rp[N+1] | dinv[N] | bsums[128] | esrc[E] | bufA[N*128]
    char* p = (char*)d_ws;
    auto alloc = [&](size_t bytes) {
        char* q = p;
        p += (bytes + 511) & ~(size_t)511;
        return q;
    };
    int* cnt = (int*)alloc((size_t)2 * N * sizeof(int));  // cnt + cur adjacent
    int* cur = cnt + N;
    int* rp = (int*)alloc((size_t)(N + 1) * sizeof(int));
    float* dinv = (float*)alloc((size_t)N * sizeof(float));
    int* bsums = (int*)alloc(128 * sizeof(int));
    int* esrc = (int*)alloc((size_t)E * sizeof(int));
    float* bufA = (float*)alloc((size_t)N * NDIM * sizeof(float));
    (void)ws_size;

    const int NB = (N + SCAN_IPB - 1) / SCAN_IPB;  // 98 for N=100k (<=128 required)

    // CSR build
    hipMemsetAsync(cnt, 0, (size_t)2 * N * sizeof(int), stream);
    degree_count<<<(E + 255) / 256, 256, 0, stream>>>(dst, cnt, E);
    scan_blocks<<<NB, SCAN_BLK, 0, stream>>>(cnt, rp, bsums, N);
    scan_partials<<<1, 128, 0, stream>>>(bsums, NB);
    add_offsets<<<(N + 255) / 256, 256, 0, stream>>>(rp, bsums, N, E);
    finalize_dinv<<<(N + 255) / 256, 256, 0, stream>>>(cnt, dinv, N);
    fill_edges<<<(E + 255) / 256, 256, 0, stream>>>(src, dst, rp, cur, esrc, E);

    dim3 ggrid((N + 63) / 64, 2);
    const int agg_blocks = ((size_t)N * 32 + 255) / 256;

    // layer 1
    gemm128<<<ggrid, 256, 0, stream>>>(emb, x, W1, bufA, N);
    aggregate_csr<<<agg_blocks, 256, 0, stream>>>(bufA, rp, esrc, dinv, b1, out, N);
    // layer 2
    gemm128<<<ggrid, 256, 0, stream>>>(out, nullptr, W2, bufA, N);
    aggregate_csr<<<agg_blocks, 256, 0, stream>>>(bufA, rp, esrc, dinv, b2, out, N);
}

// Round 3
// 325.092 us; speedup vs baseline: 7.1366x; 1.1779x over previous
//
#include <hip/hip_runtime.h>

// GCN 2-layer, bf16-MFMA GEMM + CSR atomic-free aggregation.
// h1 = relu(Anorm @ (emb[x] @ W1) + b1); out = relu(Anorm @ (h1 @ W2) + b2)
// Anorm = D^-1/2 (A+I) D^-1/2; self-loop folded into aggregation (dinv^2 term).

#define NDIM 128
#define PAD_K 136  // LDS k-stride in elements (+8 = 16B pad, balanced banks, keeps 16B align)
#define SCAN_IPT 4
#define SCAN_BLK 256
#define SCAN_IPB (SCAN_BLK * SCAN_IPT)

typedef __bf16 bf16x8 __attribute__((ext_vector_type(8)));
typedef __bf16 bf16x4 __attribute__((ext_vector_type(4)));
typedef float f32x4 __attribute__((ext_vector_type(4)));

__device__ __forceinline__ float bf2f(unsigned short u) {
    union { unsigned int i; float f; } c;
    c.i = (unsigned int)u << 16;
    return c.f;
}
__device__ __forceinline__ unsigned short f2bf(float f) {
    __bf16 b = (__bf16)f;
    return __builtin_bit_cast(unsigned short, b);
}

// ---------------- CSR build ----------------
__global__ void degree_count(const int* __restrict__ dst, int* __restrict__ cnt, int E) {
    int e = blockIdx.x * blockDim.x + threadIdx.x;
    if (e < E) atomicAdd(&cnt[dst[e]], 1);
}

__global__ void scan_blocks(const int* __restrict__ in, int* __restrict__ out,
                            int* __restrict__ bsums, int n) {
    __shared__ int lds[SCAN_BLK];
    const int t = threadIdx.x;
    const int base = blockIdx.x * SCAN_IPB + t * SCAN_IPT;
    int v[SCAN_IPT];
    int s = 0;
#pragma unroll
    for (int k = 0; k < SCAN_IPT; ++k) { v[k] = (base + k < n) ? in[base + k] : 0; s += v[k]; }
    lds[t] = s;
    __syncthreads();
    for (int off = 1; off < SCAN_BLK; off <<= 1) {
        int x = (t >= off) ? lds[t - off] : 0;
        __syncthreads();
        lds[t] += x;
        __syncthreads();
    }
    if (t == SCAN_BLK - 1) bsums[blockIdx.x] = lds[t];
    int run = (t == 0) ? 0 : lds[t - 1];
#pragma unroll
    for (int k = 0; k < SCAN_IPT; ++k) {
        if (base + k < n) out[base + k] = run;
        run += v[k];
    }
}

__global__ void scan_partials(int* __restrict__ bsums, int nb) {
    __shared__ int lds[128];
    const int t = threadIdx.x;
    lds[t] = (t < nb) ? bsums[t] : 0;
    __syncthreads();
    for (int off = 1; off < 128; off <<= 1) {
        int x = (t >= off) ? lds[t - off] : 0;
        __syncthreads();
        lds[t] += x;
        __syncthreads();
    }
    if (t < nb) bsums[t] = (t == 0) ? 0 : lds[t - 1];
}

__global__ void add_offsets_dinv(int* __restrict__ rp, const int* __restrict__ bsums,
                                 const int* __restrict__ cnt, float* __restrict__ dinv,
                                 int n, int E) {
    int i = blockIdx.x * blockDim.x + threadIdx.x;
    if (i < n) {
        rp[i] += bsums[i / SCAN_IPB];
        dinv[i] = rsqrtf((float)cnt[i] + 1.0f);  // +1 self-loop
    }
    if (i == 0) rp[n] = E;
}

__global__ void fill_edges(const int* __restrict__ src, const int* __restrict__ dst,
                           const int* __restrict__ rp, int* __restrict__ cur,
                           int* __restrict__ esrc, int E) {
    int e = blockIdx.x * blockDim.x + threadIdx.x;
    if (e >= E) return;
    int d = dst[e];
    int p = rp[d] + atomicAdd(&cur[d], 1);
    esrc[p] = src[e];
}

// ---------------- W transpose+convert (both layers, one launch) ----------------
__global__ void wt_convert2(const float* __restrict__ W1, const float* __restrict__ W2,
                            unsigned short* __restrict__ WT1, unsigned short* __restrict__ WT2) {
    int c = blockIdx.x * blockDim.x + threadIdx.x;  // 0..32767
    int cc = c & 16383;
    int j = cc >> 7, k = cc & 127;
    if (c < 16384) WT1[cc] = f2bf(W1[k * 128 + j]);
    else           WT2[cc] = f2bf(W2[k * 128 + j]);
}

// ---------------- bf16 MFMA GEMM: out[r][:] = A[r][:] @ W  (M x 128 x 128) ----------------
// MODE 0: A row r = fp32 Hsrc[idx[r]] (gather+convert).  MODE 1: A row r = bf16 Hsrc[r].
// Block: 256 threads (4 waves), 128 rows x 128 cols. Wave w: rows [32w,32w+32).
// mfma_f32_16x16x32_bf16; A-frag A[m=lane&15][k=quad*8+j]; B-frag B[k=quad*8+j][n=lane&15]
// (so B^T staged row-major [n][k]); C/D: col=lane&15, row=quad*4+reg.
template <int MODE>
__global__ __launch_bounds__(256, 2)
void gemm_mfma(const void* __restrict__ Hsrc, const int* __restrict__ idx,
               const unsigned short* __restrict__ WTb, unsigned short* __restrict__ outb,
               int n) {
    __shared__ __bf16 sA[128 * PAD_K];
    __shared__ __bf16 sBT[128 * PAD_K];
    const int tid = threadIdx.x;
    const int rbase = blockIdx.x * 128;

    // stage B^T (32 KB bf16, already transposed in global)
    {
        const uint4* src = (const uint4*)WTb;
#pragma unroll
        for (int i = 0; i < 8; ++i) {
            int c = tid + i * 256;          // 2048 x 16B
            int j = c >> 4, u = c & 15;
            *(uint4*)&sBT[j * PAD_K + u * 8] = src[c];
        }
    }
    // stage A
    if (MODE == 0) {
        const float* H = (const float*)Hsrc;
#pragma unroll
        for (int i = 0; i < 16; ++i) {
            int c = tid + i * 256;          // 4096 float4 chunks
            int r = c >> 5, c4 = c & 31;
            int gr = rbase + r;
            int srow = (gr < n) ? idx[gr] : 0;
            float4 v = ((const float4*)H)[(size_t)srow * 32 + c4];
            bf16x4 w = { (__bf16)v.x, (__bf16)v.y, (__bf16)v.z, (__bf16)v.w };
            *(bf16x4*)&sA[r * PAD_K + c4 * 4] = w;
        }
    } else {
        const unsigned short* H = (const unsigned short*)Hsrc;
#pragma unroll
        for (int i = 0; i < 8; ++i) {
            int c = tid + i * 256;          // 2048 x 16B (8 bf16)
            int r = c >> 4, u = c & 15;
            int gr = rbase + r;
            int srow = (gr < n) ? gr : 0;
            uint4 v = ((const uint4*)(H + (size_t)srow * 128))[u];
            *(uint4*)&sA[r * PAD_K + u * 8] = v;
        }
    }
    __syncthreads();

    const int wave = tid >> 6, lane = tid & 63;
    const int quad = lane >> 4, lrow = lane & 15;

    f32x4 acc[2][8];
#pragma unroll
    for (int mt = 0; mt < 2; ++mt)
#pragma unroll
        for (int nt = 0; nt < 8; ++nt) acc[mt][nt] = (f32x4)0.0f;

#pragma unroll
    for (int ks = 0; ks < 4; ++ks) {
        const int kb = ks * 32 + quad * 8;
        bf16x8 a0 = *(const bf16x8*)&sA[(wave * 32 + lrow) * PAD_K + kb];
        bf16x8 a1 = *(const bf16x8*)&sA[(wave * 32 + 16 + lrow) * PAD_K + kb];
#pragma unroll
        for (int nt = 0; nt < 8; ++nt) {
            bf16x8 b = *(const bf16x8*)&sBT[(nt * 16 + lrow) * PAD_K + kb];
            acc[0][nt] = __builtin_amdgcn_mfma_f32_16x16x32_bf16(a0, b, acc[0][nt], 0, 0, 0);
            acc[1][nt] = __builtin_amdgcn_mfma_f32_16x16x32_bf16(a1, b, acc[1][nt], 0, 0, 0);
        }
    }

    // store: row = rbase + 32*wave + 16*mt + 4*quad + r, col = 16*nt + lrow
#pragma unroll
    for (int mt = 0; mt < 2; ++mt) {
#pragma unroll
        for (int r = 0; r < 4; ++r) {
            int grow = rbase + wave * 32 + mt * 16 + quad * 4 + r;
            if (grow < n) {
                unsigned short* orow = outb + (size_t)grow * NDIM + lrow;
#pragma unroll
                for (int nt = 0; nt < 8; ++nt)
                    orow[nt * 16] = f2bf(acc[mt][nt][r]);
            }
        }
    }
}

// ---------------- aggregation: 32 lanes per dst row, bf16 gather, fp32 accum ----------------
template <bool OUT_BF16>
__global__ void aggregate_csr(const unsigned short* __restrict__ hwb, const int* __restrict__ rp,
                              const int* __restrict__ esrc, const float* __restrict__ dinv,
                              const float* __restrict__ bias, void* __restrict__ out, int n) {
    int t = blockIdx.x * blockDim.x + threadIdx.x;
    int i = t >> 5, lane = t & 31;
    if (i >= n) return;
    float di = dinv[i];
    float self = di * di;
    ushort4 u = ((const ushort4*)(hwb + (size_t)i * NDIM))[lane];
    float4 acc = make_float4(self * bf2f(u.x), self * bf2f(u.y),
                             self * bf2f(u.z), self * bf2f(u.w));
    int beg = rp[i], end = rp[i + 1];
    for (int j = beg; j < end; ++j) {
        int s = esrc[j];
        float nm = di * dinv[s];
        ushort4 v = ((const ushort4*)(hwb + (size_t)s * NDIM))[lane];
        acc.x = fmaf(nm, bf2f(v.x), acc.x);
        acc.y = fmaf(nm, bf2f(v.y), acc.y);
        acc.z = fmaf(nm, bf2f(v.z), acc.z);
        acc.w = fmaf(nm, bf2f(v.w), acc.w);
    }
    float4 b = ((const float4*)bias)[lane];
    acc.x = fmaxf(acc.x + b.x, 0.0f);
    acc.y = fmaxf(acc.y + b.y, 0.0f);
    acc.z = fmaxf(acc.z + b.z, 0.0f);
    acc.w = fmaxf(acc.w + b.w, 0.0f);
    if (OUT_BF16) {
        ushort4 o = make_ushort4(f2bf(acc.x), f2bf(acc.y), f2bf(acc.z), f2bf(acc.w));
        ((ushort4*)out)[(size_t)i * 32 + lane] = o;
    } else {
        ((float4*)out)[(size_t)i * 32 + lane] = acc;
    }
}

extern "C" void kernel_launch(void* const* d_in, const int* in_sizes, int n_in,
                              void* d_out, int out_size, void* d_ws, size_t ws_size,
                              hipStream_t stream) {
    const int* x = (const int*)d_in[0];
    const int* edge_index = (const int*)d_in[1];
    const float* emb = (const float*)d_in[2];
    const float* W1 = (const float*)d_in[3];
    const float* b1 = (const float*)d_in[4];
    const float* W2 = (const float*)d_in[5];
    const float* b2 = (const float*)d_in[6];
    float* out = (float*)d_out;

    const int N = in_sizes[0];
    const int E = in_sizes[1] / 2;
    const int* src = edge_index;
    const int* dst = edge_index + E;

    char* p = (char*)d_ws;
    auto alloc = [&](size_t bytes) {
        char* q = p;
        p += (bytes + 511) & ~(size_t)511;
        return q;
    };
    int* cnt = (int*)alloc((size_t)2 * N * sizeof(int));  // cnt + cur, one memset
    int* cur = cnt + N;
    int* rp = (int*)alloc((size_t)(N + 1) * sizeof(int));
    float* dinv = (float*)alloc((size_t)N * sizeof(float));
    int* bsums = (int*)alloc(128 * sizeof(int));
    int* esrc = (int*)alloc((size_t)E * sizeof(int));
    unsigned short* WT1 = (unsigned short*)alloc(16384 * sizeof(unsigned short));
    unsigned short* WT2 = (unsigned short*)alloc(16384 * sizeof(unsigned short));
    unsigned short* hwb = (unsigned short*)alloc((size_t)N * NDIM * sizeof(unsigned short));
    unsigned short* h1b = (unsigned short*)alloc((size_t)N * NDIM * sizeof(unsigned short));
    (void)ws_size;

    const int NB = (N + SCAN_IPB - 1) / SCAN_IPB;  // 98 <= 128

    // CSR build + dinv
    hipMemsetAsync(cnt, 0, (size_t)2 * N * sizeof(int), stream);
    degree_count<<<(E + 255) / 256, 256, 0, stream>>>(dst, cnt, E);
    scan_blocks<<<NB, SCAN_BLK, 0, stream>>>(cnt, rp, bsums, N);
    scan_partials<<<1, 128, 0, stream>>>(bsums, NB);
    add_offsets_dinv<<<(N + 255) / 256, 256, 0, stream>>>(rp, bsums, cnt, dinv, N, E);
    fill_edges<<<(E + 255) / 256, 256, 0, stream>>>(src, dst, rp, cur, esrc, E);

    // weights -> bf16 transposed
    wt_convert2<<<128, 256, 0, stream>>>(W1, W2, WT1, WT2);

    const int gemm_blocks = (N + 127) / 128;
    const int agg_blocks = (int)(((size_t)N * 32 + 255) / 256);

    // layer 1
    gemm_mfma<0><<<gemm_blocks, 256, 0, stream>>>(emb, x, WT1, hwb, N);
    aggregate_csr<true><<<agg_blocks, 256, 0, stream>>>(hwb, rp, esrc, dinv, b1, h1b, N);
    // layer 2
    gemm_mfma<1><<<gemm_blocks, 256, 0, stream>>>(h1b, nullptr, WT2, hwb, N);
    aggregate_csr<false><<<agg_blocks, 256, 0, stream>>>(hwb, rp, esrc, dinv, b2, out, N);
}

// Round 4
// 275.817 us; speedup vs baseline: 8.4116x; 1.1787x over previous
//
#include <hip/hip_runtime.h>

// GCN 2-layer, bf16-MFMA GEMM + CSR atomic-free aggregation.
// h1 = relu(Anorm @ (emb[x] @ W1) + b1); out = relu(Anorm @ (h1 @ W2) + b2)
// Anorm = D^-1/2 (A+I) D^-1/2.
// GEMM epilogue pre-scales each row by dinv[row], so the aggregate inner loop is
// pure gather+add:  out_i = relu(dinv_i * (sum_{s in N(i)} vs_s + vs_i) + b),
// where vs_r = dinv_r * (h@W)_r  (self-loop = the vs_i term).

#define NDIM 128
#define PAD_K 136  // LDS k-stride (+8 elems = 16B pad, balanced banks, keeps 16B align)
#define SCAN_IPT 4
#define SCAN_BLK 256
#define SCAN_IPB (SCAN_BLK * SCAN_IPT)

typedef __bf16 bf16x8 __attribute__((ext_vector_type(8)));
typedef __bf16 bf16x4 __attribute__((ext_vector_type(4)));
typedef float f32x4 __attribute__((ext_vector_type(4)));

__device__ __forceinline__ float bf2f(unsigned short u) {
    union { unsigned int i; float f; } c;
    c.i = (unsigned int)u << 16;
    return c.f;
}
__device__ __forceinline__ unsigned short f2bf(float f) {
    __bf16 b = (__bf16)f;
    return __builtin_bit_cast(unsigned short, b);
}

// ---------------- CSR build ----------------
__global__ void degree_count(const int* __restrict__ dst, int* __restrict__ cnt, int E) {
    int e = blockIdx.x * blockDim.x + threadIdx.x;
    if (e < E) atomicAdd(&cnt[dst[e]], 1);
}

__global__ void scan_blocks(const int* __restrict__ in, int* __restrict__ out,
                            int* __restrict__ bsums, int n) {
    __shared__ int lds[SCAN_BLK];
    const int t = threadIdx.x;
    const int base = blockIdx.x * SCAN_IPB + t * SCAN_IPT;
    int v[SCAN_IPT];
    int s = 0;
#pragma unroll
    for (int k = 0; k < SCAN_IPT; ++k) { v[k] = (base + k < n) ? in[base + k] : 0; s += v[k]; }
    lds[t] = s;
    __syncthreads();
    for (int off = 1; off < SCAN_BLK; off <<= 1) {
        int x = (t >= off) ? lds[t - off] : 0;
        __syncthreads();
        lds[t] += x;
        __syncthreads();
    }
    if (t == SCAN_BLK - 1) bsums[blockIdx.x] = lds[t];
    int run = (t == 0) ? 0 : lds[t - 1];
#pragma unroll
    for (int k = 0; k < SCAN_IPT; ++k) {
        if (base + k < n) out[base + k] = run;
        run += v[k];
    }
}

__global__ void scan_partials(int* __restrict__ bsums, int nb) {
    __shared__ int lds[128];
    const int t = threadIdx.x;
    lds[t] = (t < nb) ? bsums[t] : 0;
    __syncthreads();
    for (int off = 1; off < 128; off <<= 1) {
        int x = (t >= off) ? lds[t - off] : 0;
        __syncthreads();
        lds[t] += x;
        __syncthreads();
    }
    if (t < nb) bsums[t] = (t == 0) ? 0 : lds[t - 1];
}

__global__ void add_offsets_dinv(int* __restrict__ rp, const int* __restrict__ bsums,
                                 const int* __restrict__ cnt, float* __restrict__ dinv,
                                 int n, int E) {
    int i = blockIdx.x * blockDim.x + threadIdx.x;
    if (i < n) {
        rp[i] += bsums[i / SCAN_IPB];
        dinv[i] = rsqrtf((float)cnt[i] + 1.0f);  // +1 self-loop
    }
    if (i == 0) rp[n] = E;
}

__global__ void fill_edges(const int* __restrict__ src, const int* __restrict__ dst,
                           const int* __restrict__ rp, int* __restrict__ cur,
                           int* __restrict__ esrc, int E) {
    int e = blockIdx.x * blockDim.x + threadIdx.x;
    if (e >= E) return;
    int d = dst[e];
    int p = rp[d] + atomicAdd(&cur[d], 1);
    esrc[p] = src[e];
}

// ---------------- W transpose+convert (both layers, one launch) ----------------
__global__ void wt_convert2(const float* __restrict__ W1, const float* __restrict__ W2,
                            unsigned short* __restrict__ WT1, unsigned short* __restrict__ WT2) {
    int c = blockIdx.x * blockDim.x + threadIdx.x;  // 0..32767
    int cc = c & 16383;
    int j = cc >> 7, k = cc & 127;
    if (c < 16384) WT1[cc] = f2bf(W1[k * 128 + j]);
    else           WT2[cc] = f2bf(W2[k * 128 + j]);
}

// ---------------- bf16 MFMA GEMM: outb[r][:] = dinv[r] * (A[r][:] @ W) ----------------
// MODE 0: A row r = fp32 Hsrc[idx[r]] (gather+convert).  MODE 1: A row r = bf16 Hsrc[r].
// Block: 256 threads (4 waves), 128 rows x 128 cols. Wave w: rows [32w,32w+32).
// mfma_f32_16x16x32_bf16; A-frag A[m=lane&15][k=quad*8+j]; B-frag B[k=quad*8+j][n=lane&15]
// (B^T staged row-major [n][k]); C/D: col=lane&15, row=quad*4+reg.
template <int MODE>
__global__ __launch_bounds__(256, 2)
void gemm_mfma(const void* __restrict__ Hsrc, const int* __restrict__ idx,
               const unsigned short* __restrict__ WTb, const float* __restrict__ dinv,
               unsigned short* __restrict__ outb, int n) {
    __shared__ __bf16 sA[128 * PAD_K];
    __shared__ __bf16 sBT[128 * PAD_K];
    const int tid = threadIdx.x;
    const int rbase = blockIdx.x * 128;

    // stage B^T (32 KB bf16, already transposed in global)
    {
        const uint4* src = (const uint4*)WTb;
#pragma unroll
        for (int i = 0; i < 8; ++i) {
            int c = tid + i * 256;          // 2048 x 16B
            int j = c >> 4, u = c & 15;
            *(uint4*)&sBT[j * PAD_K + u * 8] = src[c];
        }
    }
    // stage A
    if (MODE == 0) {
        const float* H = (const float*)Hsrc;
#pragma unroll
        for (int i = 0; i < 16; ++i) {
            int c = tid + i * 256;          // 4096 float4 chunks
            int r = c >> 5, c4 = c & 31;
            int gr = rbase + r;
            int srow = (gr < n) ? idx[gr] : 0;
            float4 v = ((const float4*)H)[(size_t)srow * 32 + c4];
            bf16x4 w = { (__bf16)v.x, (__bf16)v.y, (__bf16)v.z, (__bf16)v.w };
            *(bf16x4*)&sA[r * PAD_K + c4 * 4] = w;
        }
    } else {
        const unsigned short* H = (const unsigned short*)Hsrc;
#pragma unroll
        for (int i = 0; i < 8; ++i) {
            int c = tid + i * 256;          // 2048 x 16B (8 bf16)
            int r = c >> 4, u = c & 15;
            int gr = rbase + r;
            int srow = (gr < n) ? gr : 0;
            uint4 v = ((const uint4*)(H + (size_t)srow * 128))[u];
            *(uint4*)&sA[r * PAD_K + u * 8] = v;
        }
    }
    __syncthreads();

    const int wave = tid >> 6, lane = tid & 63;
    const int quad = lane >> 4, lrow = lane & 15;

    f32x4 acc[2][8];
#pragma unroll
    for (int mt = 0; mt < 2; ++mt)
#pragma unroll
        for (int nt = 0; nt < 8; ++nt) acc[mt][nt] = (f32x4)0.0f;

#pragma unroll
    for (int ks = 0; ks < 4; ++ks) {
        const int kb = ks * 32 + quad * 8;
        bf16x8 a0 = *(const bf16x8*)&sA[(wave * 32 + lrow) * PAD_K + kb];
        bf16x8 a1 = *(const bf16x8*)&sA[(wave * 32 + 16 + lrow) * PAD_K + kb];
#pragma unroll
        for (int nt = 0; nt < 8; ++nt) {
            bf16x8 b = *(const bf16x8*)&sBT[(nt * 16 + lrow) * PAD_K + kb];
            acc[0][nt] = __builtin_amdgcn_mfma_f32_16x16x32_bf16(a0, b, acc[0][nt], 0, 0, 0);
            acc[1][nt] = __builtin_amdgcn_mfma_f32_16x16x32_bf16(a1, b, acc[1][nt], 0, 0, 0);
        }
    }

    // store scaled by dinv[row]: row = rbase + 32*wave + 16*mt + 4*quad + r, col = 16*nt + lrow
#pragma unroll
    for (int mt = 0; mt < 2; ++mt) {
#pragma unroll
        for (int r = 0; r < 4; ++r) {
            int grow = rbase + wave * 32 + mt * 16 + quad * 4 + r;
            if (grow < n) {
                float dsc = dinv[grow];
                unsigned short* orow = outb + (size_t)grow * NDIM + lrow;
#pragma unroll
                for (int nt = 0; nt < 8; ++nt)
                    orow[nt * 16] = f2bf(dsc * acc[mt][nt][r]);
            }
        }
    }
}

// ---------------- aggregation: 32 lanes per dst row, unroll-4 gather, fp32 accum ----------------
// vs = pre-scaled rows (dinv[r]*hw[r]).  out_i = relu(dinv_i*(sum_edges vs_s + vs_i) + b)
template <bool OUT_BF16>
__global__ void aggregate_csr(const unsigned short* __restrict__ vs, const int* __restrict__ rp,
                              const int* __restrict__ esrc, const float* __restrict__ dinv,
                              const float* __restrict__ bias, void* __restrict__ out, int n) {
    int t = blockIdx.x * blockDim.x + threadIdx.x;
    int i = t >> 5, lane = t & 31;
    if (i >= n) return;
    const ushort4* vs4 = (const ushort4*)vs;  // row = 32 x ushort4
    ushort4 u = vs4[(size_t)i * 32 + lane];   // self term
    float4 acc = make_float4(bf2f(u.x), bf2f(u.y), bf2f(u.z), bf2f(u.w));
    int j = rp[i];
    const int end = rp[i + 1];
    for (; j + 4 <= end; j += 4) {
        int s0 = esrc[j], s1 = esrc[j + 1], s2 = esrc[j + 2], s3 = esrc[j + 3];
        ushort4 v0 = vs4[(size_t)s0 * 32 + lane];
        ushort4 v1 = vs4[(size_t)s1 * 32 + lane];
        ushort4 v2 = vs4[(size_t)s2 * 32 + lane];
        ushort4 v3 = vs4[(size_t)s3 * 32 + lane];
        acc.x += (bf2f(v0.x) + bf2f(v1.x)) + (bf2f(v2.x) + bf2f(v3.x));
        acc.y += (bf2f(v0.y) + bf2f(v1.y)) + (bf2f(v2.y) + bf2f(v3.y));
        acc.z += (bf2f(v0.z) + bf2f(v1.z)) + (bf2f(v2.z) + bf2f(v3.z));
        acc.w += (bf2f(v0.w) + bf2f(v1.w)) + (bf2f(v2.w) + bf2f(v3.w));
    }
    for (; j < end; ++j) {
        int s = esrc[j];
        ushort4 v = vs4[(size_t)s * 32 + lane];
        acc.x += bf2f(v.x);
        acc.y += bf2f(v.y);
        acc.z += bf2f(v.z);
        acc.w += bf2f(v.w);
    }
    float di = dinv[i];
    float4 b = ((const float4*)bias)[lane];
    acc.x = fmaxf(fmaf(di, acc.x, b.x), 0.0f);
    acc.y = fmaxf(fmaf(di, acc.y, b.y), 0.0f);
    acc.z = fmaxf(fmaf(di, acc.z, b.z), 0.0f);
    acc.w = fmaxf(fmaf(di, acc.w, b.w), 0.0f);
    if (OUT_BF16) {
        ushort4 o = make_ushort4(f2bf(acc.x), f2bf(acc.y), f2bf(acc.z), f2bf(acc.w));
        ((ushort4*)out)[(size_t)i * 32 + lane] = o;
    } else {
        ((float4*)out)[(size_t)i * 32 + lane] = acc;
    }
}

extern "C" void kernel_launch(void* const* d_in, const int* in_sizes, int n_in,
                              void* d_out, int out_size, void* d_ws, size_t ws_size,
                              hipStream_t stream) {
    const int* x = (const int*)d_in[0];
    const int* edge_index = (const int*)d_in[1];
    const float* emb = (const float*)d_in[2];
    const float* W1 = (const float*)d_in[3];
    const float* b1 = (const float*)d_in[4];
    const float* W2 = (const float*)d_in[5];
    const float* b2 = (const float*)d_in[6];
    float* out = (float*)d_out;

    const int N = in_sizes[0];
    const int E = in_sizes[1] / 2;
    const int* src = edge_index;
    const int* dst = edge_index + E;

    char* p = (char*)d_ws;
    auto alloc = [&](size_t bytes) {
        char* q = p;
        p += (bytes + 511) & ~(size_t)511;
        return q;
    };
    int* cnt = (int*)alloc((size_t)2 * N * sizeof(int));  // cnt + cur, one memset
    int* cur = cnt + N;
    int* rp = (int*)alloc((size_t)(N + 1) * sizeof(int));
    float* dinv = (float*)alloc((size_t)N * sizeof(float));
    int* bsums = (int*)alloc(128 * sizeof(int));
    int* esrc = (int*)alloc((size_t)E * sizeof(int));
    unsigned short* WT1 = (unsigned short*)alloc(16384 * sizeof(unsigned short));
    unsigned short* WT2 = (unsigned short*)alloc(16384 * sizeof(unsigned short));
    unsigned short* hwb = (unsigned short*)alloc((size_t)N * NDIM * sizeof(unsigned short));
    unsigned short* h1b = (unsigned short*)alloc((size_t)N * NDIM * sizeof(unsigned short));
    (void)ws_size;

    const int NB = (N + SCAN_IPB - 1) / SCAN_IPB;  // 98 <= 128

    // CSR build + dinv
    hipMemsetAsync(cnt, 0, (size_t)2 * N * sizeof(int), stream);
    degree_count<<<(E + 255) / 256, 256, 0, stream>>>(dst, cnt, E);
    scan_blocks<<<NB, SCAN_BLK, 0, stream>>>(cnt, rp, bsums, N);
    scan_partials<<<1, 128, 0, stream>>>(bsums, NB);
    add_offsets_dinv<<<(N + 255) / 256, 256, 0, stream>>>(rp, bsums, cnt, dinv, N, E);
    fill_edges<<<(E + 255) / 256, 256, 0, stream>>>(src, dst, rp, cur, esrc, E);

    // weights -> bf16 transposed
    wt_convert2<<<128, 256, 0, stream>>>(W1, W2, WT1, WT2);

    const int gemm_blocks = (N + 127) / 128;
    const int agg_blocks = (int)(((size_t)N * 32 + 255) / 256);

    // layer 1
    gemm_mfma<0><<<gemm_blocks, 256, 0, stream>>>(emb, x, WT1, dinv, hwb, N);
    aggregate_csr<true><<<agg_blocks, 256, 0, stream>>>(hwb, rp, esrc, dinv, b1, h1b, N);
    // layer 2
    gemm_mfma<1><<<gemm_blocks, 256, 0, stream>>>(h1b, nullptr, WT2, dinv, hwb, N);
    aggregate_csr<false><<<agg_blocks, 256, 0, stream>>>(hwb, rp, esrc, dinv, b2, out, N);
}

// Round 5
// 258.351 us; speedup vs baseline: 8.9802x; 1.0676x over previous
//
#include <hip/hip_runtime.h>

// GCN 2-layer, bf16-MFMA GEMM + CSR atomic-free aggregation.
// h1 = relu(Anorm @ (emb[x] @ W1) + b1); out = relu(Anorm @ (h1 @ W2) + b2)
// Anorm = D^-1/2 (A+I) D^-1/2.
// Key algebraic move: (emb[x]) @ W1 == (emb @ W1)[x]  -> layer-1 GEMM runs over the
// 50k-row vocab table with SEQUENTIAL A, then a cheap gather produces per-node rows.
// Rows entering aggregation are pre-scaled by dinv, so the edge loop is pure gather+add:
//   out_i = relu(dinv_i * (sum_{s in N(i)} vs_s + vs_i) + b),  vs_r = dinv_r * (h@W)_r.

#define NDIM 128
#define PAD_K 136  // LDS k-stride (+8 elems = 16B pad; fragment reads ~2-way = free)
#define SCAN_IPT 4
#define SCAN_BLK 256
#define SCAN_IPB (SCAN_BLK * SCAN_IPT)

typedef __bf16 bf16x8 __attribute__((ext_vector_type(8)));
typedef __bf16 bf16x4 __attribute__((ext_vector_type(4)));
typedef float f32x4 __attribute__((ext_vector_type(4)));

__device__ __forceinline__ float bf2f(unsigned short u) {
    union { unsigned int i; float f; } c;
    c.i = (unsigned int)u << 16;
    return c.f;
}
__device__ __forceinline__ unsigned short f2bf(float f) {
    __bf16 b = (__bf16)f;
    return __builtin_bit_cast(unsigned short, b);
}

// ---------------- CSR build ----------------
__global__ void degree_count(const int* __restrict__ dst, int* __restrict__ cnt, int E) {
    int e = blockIdx.x * blockDim.x + threadIdx.x;
    if (e < E) atomicAdd(&cnt[dst[e]], 1);
}

__global__ void scan_blocks(const int* __restrict__ in, int* __restrict__ out,
                            int* __restrict__ bsums, int n) {
    __shared__ int lds[SCAN_BLK];
    const int t = threadIdx.x;
    const int base = blockIdx.x * SCAN_IPB + t * SCAN_IPT;
    int v[SCAN_IPT];
    int s = 0;
#pragma unroll
    for (int k = 0; k < SCAN_IPT; ++k) { v[k] = (base + k < n) ? in[base + k] : 0; s += v[k]; }
    lds[t] = s;
    __syncthreads();
    for (int off = 1; off < SCAN_BLK; off <<= 1) {
        int x = (t >= off) ? lds[t - off] : 0;
        __syncthreads();
        lds[t] += x;
        __syncthreads();
    }
    if (t == SCAN_BLK - 1) bsums[blockIdx.x] = lds[t];
    int run = (t == 0) ? 0 : lds[t - 1];
#pragma unroll
    for (int k = 0; k < SCAN_IPT; ++k) {
        if (base + k < n) out[base + k] = run;
        run += v[k];
    }
}

__global__ void scan_partials(int* __restrict__ bsums, int nb) {
    __shared__ int lds[128];
    const int t = threadIdx.x;
    lds[t] = (t < nb) ? bsums[t] : 0;
    __syncthreads();
    for (int off = 1; off < 128; off <<= 1) {
        int x = (t >= off) ? lds[t - off] : 0;
        __syncthreads();
        lds[t] += x;
        __syncthreads();
    }
    if (t < nb) bsums[t] = (t == 0) ? 0 : lds[t - 1];
}

__global__ void add_offsets_dinv(int* __restrict__ rp, const int* __restrict__ bsums,
                                 const int* __restrict__ cnt, float* __restrict__ dinv,
                                 int n, int E) {
    int i = blockIdx.x * blockDim.x + threadIdx.x;
    if (i < n) {
        rp[i] += bsums[i / SCAN_IPB];
        dinv[i] = rsqrtf((float)cnt[i] + 1.0f);  // +1 self-loop
    }
    if (i == 0) rp[n] = E;
}

__global__ void fill_edges(const int* __restrict__ src, const int* __restrict__ dst,
                           const int* __restrict__ rp, int* __restrict__ cur,
                           int* __restrict__ esrc, int E) {
    int e = blockIdx.x * blockDim.x + threadIdx.x;
    if (e >= E) return;
    int d = dst[e];
    int p = rp[d] + atomicAdd(&cur[d], 1);
    esrc[p] = src[e];
}

// ---------------- W transpose+convert (both layers, one launch) ----------------
__global__ void wt_convert2(const float* __restrict__ W1, const float* __restrict__ W2,
                            unsigned short* __restrict__ WT1, unsigned short* __restrict__ WT2) {
    int c = blockIdx.x * blockDim.x + threadIdx.x;  // 0..32767
    int cc = c & 16383;
    int j = cc >> 7, k = cc & 127;
    if (c < 16384) WT1[cc] = f2bf(W1[k * 128 + j]);
    else           WT2[cc] = f2bf(W2[k * 128 + j]);
}

// ---------------- bf16 MFMA GEMM: outb[r][:] = (dinv[r]?) * (A[r][:] @ W) ----------------
// MODE 0: A rows fp32 (sequential, convert in staging).  MODE 1: A rows bf16.
// Block: 256 threads (4 waves), tile 64 rows x 128 cols; wave w owns rows [16w,16w+16).
// LDS 52 KB -> 3 blocks/CU.  mfma_f32_16x16x32_bf16:
// A-frag A[m=lane&15][k=quad*8+j]; B-frag B[k][n=lane&15] (B^T staged [n][k]);
// C/D: col=lane&15, row=quad*4+reg.
template <int MODE, bool SCALE>
__global__ __launch_bounds__(256, 3)
void gemm_mfma(const void* __restrict__ Asrc, const unsigned short* __restrict__ WTb,
               const float* __restrict__ dinv, unsigned short* __restrict__ outb, int n) {
    __shared__ __bf16 sA[64 * PAD_K];
    __shared__ __bf16 sBT[128 * PAD_K];
    const int tid = threadIdx.x;
    const int rbase = blockIdx.x * 64;

    // stage A (64 rows)
    if (MODE == 0) {
        const float* A = (const float*)Asrc;
#pragma unroll
        for (int i = 0; i < 8; ++i) {
            int c = tid + i * 256;          // 2048 float4
            int r = c >> 5, c4 = c & 31;
            int gr = rbase + r;
            int srow = (gr < n) ? gr : (n - 1);
            float4 v = ((const float4*)A)[(size_t)srow * 32 + c4];
            bf16x4 w = { (__bf16)v.x, (__bf16)v.y, (__bf16)v.z, (__bf16)v.w };
            *(bf16x4*)&sA[r * PAD_K + c4 * 4] = w;
        }
    } else {
        const unsigned short* A = (const unsigned short*)Asrc;
#pragma unroll
        for (int i = 0; i < 4; ++i) {
            int c = tid + i * 256;          // 1024 x 16B
            int r = c >> 4, u = c & 15;
            int gr = rbase + r;
            int srow = (gr < n) ? gr : (n - 1);
            uint4 v = ((const uint4*)(A + (size_t)srow * 128))[u];
            *(uint4*)&sA[r * PAD_K + u * 8] = v;
        }
    }
    // stage B^T (32 KB)
    {
        const uint4* bsrc = (const uint4*)WTb;
#pragma unroll
        for (int i = 0; i < 8; ++i) {
            int c = tid + i * 256;          // 2048 x 16B
            int j = c >> 4, u = c & 15;
            *(uint4*)&sBT[j * PAD_K + u * 8] = bsrc[c];
        }
    }
    __syncthreads();

    const int wave = tid >> 6, lane = tid & 63;
    const int quad = lane >> 4, lrow = lane & 15;

    f32x4 acc[8];
#pragma unroll
    for (int nt = 0; nt < 8; ++nt) acc[nt] = (f32x4)0.0f;

#pragma unroll
    for (int ks = 0; ks < 4; ++ks) {
        const int kb = ks * 32 + quad * 8;
        bf16x8 a = *(const bf16x8*)&sA[(wave * 16 + lrow) * PAD_K + kb];
#pragma unroll
        for (int nt = 0; nt < 8; ++nt) {
            bf16x8 b = *(const bf16x8*)&sBT[(nt * 16 + lrow) * PAD_K + kb];
            acc[nt] = __builtin_amdgcn_mfma_f32_16x16x32_bf16(a, b, acc[nt], 0, 0, 0);
        }
    }

    // store: row = rbase + 16*wave + 4*quad + r, col = 16*nt + lrow
#pragma unroll
    for (int r = 0; r < 4; ++r) {
        int grow = rbase + wave * 16 + quad * 4 + r;
        if (grow < n) {
            float dsc = SCALE ? dinv[grow] : 1.0f;
            unsigned short* orow = outb + (size_t)grow * NDIM + lrow;
#pragma unroll
            for (int nt = 0; nt < 8; ++nt)
                orow[nt * 16] = f2bf(SCALE ? dsc * acc[nt][r] : acc[nt][r]);
        }
    }
}

// ---------------- vs1[i][:] = bf16(dinv[i] * tab[x[i]][:])  (16 lanes/row) ----------------
__global__ void gather_scale(const unsigned short* __restrict__ tab, const int* __restrict__ x,
                             const float* __restrict__ dinv, unsigned short* __restrict__ vs,
                             int n) {
    int t = blockIdx.x * blockDim.x + threadIdx.x;
    int i = t >> 4, u = t & 15;
    if (i >= n) return;
    int row = x[i];
    float di = dinv[i];
    union { uint4 q; unsigned short s[8]; } a;
    a.q = ((const uint4*)(tab + (size_t)row * 128))[u];
#pragma unroll
    for (int k = 0; k < 8; ++k) a.s[k] = f2bf(di * bf2f(a.s[k]));
    ((uint4*)(vs + (size_t)i * 128))[u] = a.q;
}

// ---------------- aggregation: 32 lanes per dst row, unroll-4 gather, fp32 accum ----------------
template <bool OUT_BF16>
__global__ void aggregate_csr(const unsigned short* __restrict__ vs, const int* __restrict__ rp,
                              const int* __restrict__ esrc, const float* __restrict__ dinv,
                              const float* __restrict__ bias, void* __restrict__ out, int n) {
    int t = blockIdx.x * blockDim.x + threadIdx.x;
    int i = t >> 5, lane = t & 31;
    if (i >= n) return;
    const ushort4* vs4 = (const ushort4*)vs;  // row = 32 x ushort4
    ushort4 u = vs4[(size_t)i * 32 + lane];   // self term
    float4 acc = make_float4(bf2f(u.x), bf2f(u.y), bf2f(u.z), bf2f(u.w));
    int j = rp[i];
    const int end = rp[i + 1];
    for (; j + 4 <= end; j += 4) {
        int s0 = esrc[j], s1 = esrc[j + 1], s2 = esrc[j + 2], s3 = esrc[j + 3];
        ushort4 v0 = vs4[(size_t)s0 * 32 + lane];
        ushort4 v1 = vs4[(size_t)s1 * 32 + lane];
        ushort4 v2 = vs4[(size_t)s2 * 32 + lane];
        ushort4 v3 = vs4[(size_t)s3 * 32 + lane];
        acc.x += (bf2f(v0.x) + bf2f(v1.x)) + (bf2f(v2.x) + bf2f(v3.x));
        acc.y += (bf2f(v0.y) + bf2f(v1.y)) + (bf2f(v2.y) + bf2f(v3.y));
        acc.z += (bf2f(v0.z) + bf2f(v1.z)) + (bf2f(v2.z) + bf2f(v3.z));
        acc.w += (bf2f(v0.w) + bf2f(v1.w)) + (bf2f(v2.w) + bf2f(v3.w));
    }
    for (; j < end; ++j) {
        int s = esrc[j];
        ushort4 v = vs4[(size_t)s * 32 + lane];
        acc.x += bf2f(v.x);
        acc.y += bf2f(v.y);
        acc.z += bf2f(v.z);
        acc.w += bf2f(v.w);
    }
    float di = dinv[i];
    float4 b = ((const float4*)bias)[lane];
    acc.x = fmaxf(fmaf(di, acc.x, b.x), 0.0f);
    acc.y = fmaxf(fmaf(di, acc.y, b.y), 0.0f);
    acc.z = fmaxf(fmaf(di, acc.z, b.z), 0.0f);
    acc.w = fmaxf(fmaf(di, acc.w, b.w), 0.0f);
    if (OUT_BF16) {
        ushort4 o = make_ushort4(f2bf(acc.x), f2bf(acc.y), f2bf(acc.z), f2bf(acc.w));
        ((ushort4*)out)[(size_t)i * 32 + lane] = o;
    } else {
        ((float4*)out)[(size_t)i * 32 + lane] = acc;
    }
}

extern "C" void kernel_launch(void* const* d_in, const int* in_sizes, int n_in,
                              void* d_out, int out_size, void* d_ws, size_t ws_size,
                              hipStream_t stream) {
    const int* x = (const int*)d_in[0];
    const int* edge_index = (const int*)d_in[1];
    const float* emb = (const float*)d_in[2];
    const float* W1 = (const float*)d_in[3];
    const float* b1 = (const float*)d_in[4];
    const float* W2 = (const float*)d_in[5];
    const float* b2 = (const float*)d_in[6];
    float* out = (float*)d_out;

    const int N = in_sizes[0];
    const int E = in_sizes[1] / 2;
    const int V = in_sizes[2] / NDIM;  // vocab rows
    const int* src = edge_index;
    const int* dst = edge_index + E;

    char* p = (char*)d_ws;
    auto alloc = [&](size_t bytes) {
        char* q = p;
        p += (bytes + 511) & ~(size_t)511;
        return q;
    };
    int* cnt = (int*)alloc((size_t)2 * N * sizeof(int));  // cnt + cur, one memset
    int* cur = cnt + N;
    int* rp = (int*)alloc((size_t)(N + 1) * sizeof(int));
    float* dinv = (float*)alloc((size_t)N * sizeof(float));
    int* bsums = (int*)alloc(128 * sizeof(int));
    int* esrc = (int*)alloc((size_t)E * sizeof(int));
    unsigned short* WT1 = (unsigned short*)alloc(16384 * sizeof(unsigned short));
    unsigned short* WT2 = (unsigned short*)alloc(16384 * sizeof(unsigned short));
    unsigned short* embW1 = (unsigned short*)alloc((size_t)V * NDIM * sizeof(unsigned short));
    unsigned short* vs1 = (unsigned short*)alloc((size_t)N * NDIM * sizeof(unsigned short));
    unsigned short* h1b = (unsigned short*)alloc((size_t)N * NDIM * sizeof(unsigned short));
    unsigned short* vs2 = (unsigned short*)alloc((size_t)N * NDIM * sizeof(unsigned short));
    (void)ws_size;

    const int NB = (N + SCAN_IPB - 1) / SCAN_IPB;  // 98 <= 128

    // CSR build + dinv
    hipMemsetAsync(cnt, 0, (size_t)2 * N * sizeof(int), stream);
    degree_count<<<(E + 255) / 256, 256, 0, stream>>>(dst, cnt, E);
    scan_blocks<<<NB, SCAN_BLK, 0, stream>>>(cnt, rp, bsums, N);
    scan_partials<<<1, 128, 0, stream>>>(bsums, NB);
    add_offsets_dinv<<<(N + 255) / 256, 256, 0, stream>>>(rp, bsums, cnt, dinv, N, E);
    fill_edges<<<(E + 255) / 256, 256, 0, stream>>>(src, dst, rp, cur, esrc, E);

    // weights -> bf16 transposed
    wt_convert2<<<128, 256, 0, stream>>>(W1, W2, WT1, WT2);

    const int agg_blocks = (int)(((size_t)N * 32 + 255) / 256);
    const int gs_blocks = (int)(((size_t)N * 16 + 255) / 256);

    // layer 1: vocab-table GEMM, then per-node gather+scale
    gemm_mfma<0, false><<<(V + 63) / 64, 256, 0, stream>>>(emb, WT1, nullptr, embW1, V);
    gather_scale<<<gs_blocks, 256, 0, stream>>>(embW1, x, dinv, vs1, N);
    aggregate_csr<true><<<agg_blocks, 256, 0, stream>>>(vs1, rp, esrc, dinv, b1, h1b, N);
    // layer 2
    gemm_mfma<1, true><<<(N + 63) / 64, 256, 0, stream>>>(h1b, WT2, dinv, vs2, N);
    aggregate_csr<false><<<agg_blocks, 256, 0, stream>>>(vs2, rp, esrc, dinv, b2, out, N);
}

// Round 6
// 247.404 us; speedup vs baseline: 9.3776x; 1.0442x over previous
//
#include <hip/hip_runtime.h>

// GCN 2-layer, bf16-MFMA GEMM + CSR atomic-free aggregation.
// h1 = relu(Anorm @ (emb[x] @ W1) + b1); out = relu(Anorm @ (h1 @ W2) + b2)
// Anorm = D^-1/2 (A+I) D^-1/2.
// (emb[x]) @ W1 == (emb @ W1)[x]: layer-1 GEMM runs over the 50k-row vocab table.
// Aggregation is pure gather+accumulate:
//   layer1: out_i = relu(di*(sum_e wsc_e * embW1[widx_e] + di*embW1[x_i]) + b1)
//           with per-edge (widx, wsc) = (x[src], dinv[src]) precomputed in fill_edges.
//   layer2: rows pre-scaled by dinv in the GEMM epilogue (vs2), edge loop adds vs2[src].

#define NDIM 128
#define PAD_K 136  // LDS k-stride for B^T (+8 elems = 16B pad)
#define SCAN_IPT 4
#define SCAN_BLK 256
#define SCAN_IPB (SCAN_BLK * SCAN_IPT)

typedef __bf16 bf16x8 __attribute__((ext_vector_type(8)));
typedef float f32x4 __attribute__((ext_vector_type(4)));

__device__ __forceinline__ float bf2f(unsigned short u) {
    union { unsigned int i; float f; } c;
    c.i = (unsigned int)u << 16;
    return c.f;
}
__device__ __forceinline__ unsigned short f2bf(float f) {
    __bf16 b = (__bf16)f;
    return __builtin_bit_cast(unsigned short, b);
}
__device__ __forceinline__ void unpack8(uint4 q, float* f) {
    f[0] = bf2f((unsigned short)(q.x & 0xffff));
    f[1] = bf2f((unsigned short)(q.x >> 16));
    f[2] = bf2f((unsigned short)(q.y & 0xffff));
    f[3] = bf2f((unsigned short)(q.y >> 16));
    f[4] = bf2f((unsigned short)(q.z & 0xffff));
    f[5] = bf2f((unsigned short)(q.z >> 16));
    f[6] = bf2f((unsigned short)(q.w & 0xffff));
    f[7] = bf2f((unsigned short)(q.w >> 16));
}

// ---------------- CSR build ----------------
__global__ void degree_count(const int* __restrict__ dst, int* __restrict__ cnt, int E) {
    int e = blockIdx.x * blockDim.x + threadIdx.x;
    if (e < E) atomicAdd(&cnt[dst[e]], 1);
}

__global__ void scan_blocks(const int* __restrict__ in, int* __restrict__ out,
                            int* __restrict__ bsums, int n) {
    __shared__ int lds[SCAN_BLK];
    const int t = threadIdx.x;
    const int base = blockIdx.x * SCAN_IPB + t * SCAN_IPT;
    int v[SCAN_IPT];
    int s = 0;
#pragma unroll
    for (int k = 0; k < SCAN_IPT; ++k) { v[k] = (base + k < n) ? in[base + k] : 0; s += v[k]; }
    lds[t] = s;
    __syncthreads();
    for (int off = 1; off < SCAN_BLK; off <<= 1) {
        int x = (t >= off) ? lds[t - off] : 0;
        __syncthreads();
        lds[t] += x;
        __syncthreads();
    }
    if (t == SCAN_BLK - 1) bsums[blockIdx.x] = lds[t];
    int run = (t == 0) ? 0 : lds[t - 1];
#pragma unroll
    for (int k = 0; k < SCAN_IPT; ++k) {
        if (base + k < n) out[base + k] = run;
        run += v[k];
    }
}

__global__ void scan_partials(int* __restrict__ bsums, int nb) {
    __shared__ int lds[128];
    const int t = threadIdx.x;
    lds[t] = (t < nb) ? bsums[t] : 0;
    __syncthreads();
    for (int off = 1; off < 128; off <<= 1) {
        int x = (t >= off) ? lds[t - off] : 0;
        __syncthreads();
        lds[t] += x;
        __syncthreads();
    }
    if (t < nb) bsums[t] = (t == 0) ? 0 : lds[t - 1];
}

__global__ void add_offsets_dinv(int* __restrict__ rp, const int* __restrict__ bsums,
                                 const int* __restrict__ cnt, float* __restrict__ dinv, int n) {
    int i = blockIdx.x * blockDim.x + threadIdx.x;
    if (i < n) {
        rp[i] += bsums[i / SCAN_IPB];
        dinv[i] = rsqrtf((float)cnt[i] + 1.0f);  // +1 self-loop
    }
}

// Increments rp[d] in place: afterwards rp[i] == inclusive scan, so row i's edge
// range is [i==0 ? 0 : rp[i-1], rp[i]).  Also emits per-edge (x[src], dinv[src]).
__global__ void fill_edges(const int* __restrict__ src, const int* __restrict__ dst,
                           int* __restrict__ rp, const int* __restrict__ x,
                           const float* __restrict__ dinv,
                           int* __restrict__ esrc, int2* __restrict__ ew, int E) {
    int e = blockIdx.x * blockDim.x + threadIdx.x;
    if (e >= E) return;
    int d = dst[e], s = src[e];
    int p = atomicAdd(&rp[d], 1);
    esrc[p] = s;
    ew[p] = make_int2(x[s], __float_as_int(dinv[s]));
}

// ---------------- W transpose+convert (both layers, one launch) ----------------
__global__ void wt_convert2(const float* __restrict__ W1, const float* __restrict__ W2,
                            unsigned short* __restrict__ WT1, unsigned short* __restrict__ WT2) {
    int c = blockIdx.x * blockDim.x + threadIdx.x;  // 0..32767
    int cc = c & 16383;
    int j = cc >> 7, k = cc & 127;
    if (c < 16384) WT1[cc] = f2bf(W1[k * 128 + j]);
    else           WT2[cc] = f2bf(W2[k * 128 + j]);
}

// ---------------- bf16 MFMA GEMM: outb[r][:] = (dinv[r]?) * (A[r][:] @ W) ----------------
// MODE 0: A rows fp32 (sequential, convert inline).  MODE 1: A rows bf16.
// Block: 256 threads (4 waves), tile 64 rows x 128 cols; wave w rows [16w,16w+16).
// A fragments read DIRECTLY from global (16B/lane contiguous, exactly-once traffic);
// only B^T staged in LDS (34 KB -> 4 blocks/CU).  mfma_f32_16x16x32_bf16:
// A-frag A[m=lane&15][k=quad*8+j]; B-frag B[k][n=lane&15] (B^T staged [n][k]);
// C/D: col=lane&15, row=quad*4+reg.
template <int MODE, bool SCALE>
__global__ __launch_bounds__(256, 4)
void gemm_mfma(const void* __restrict__ Asrc, const unsigned short* __restrict__ WTb,
               const float* __restrict__ dinv, unsigned short* __restrict__ outb, int n) {
    __shared__ __bf16 sBT[128 * PAD_K];
    const int tid = threadIdx.x;
    const int rbase = blockIdx.x * 64;

    {
        const uint4* bsrc = (const uint4*)WTb;
#pragma unroll
        for (int i = 0; i < 8; ++i) {
            int c = tid + i * 256;          // 2048 x 16B
            int j = c >> 4, u = c & 15;
            *(uint4*)&sBT[j * PAD_K + u * 8] = bsrc[c];
        }
    }
    __syncthreads();

    const int wave = tid >> 6, lane = tid & 63;
    const int quad = lane >> 4, lrow = lane & 15;
    int arow = rbase + wave * 16 + lrow;
    if (arow >= n) arow = n - 1;  // clamp; guarded at store

    f32x4 acc[8];
#pragma unroll
    for (int nt = 0; nt < 8; ++nt) acc[nt] = (f32x4)0.0f;

#pragma unroll
    for (int ks = 0; ks < 4; ++ks) {
        const int kb = ks * 32 + quad * 8;
        bf16x8 a;
        if (MODE == 0) {
            const float4* A4 = (const float4*)Asrc;
            float4 v0 = A4[(size_t)arow * 32 + (kb >> 2)];
            float4 v1 = A4[(size_t)arow * 32 + (kb >> 2) + 1];
            a = (bf16x8){(__bf16)v0.x, (__bf16)v0.y, (__bf16)v0.z, (__bf16)v0.w,
                         (__bf16)v1.x, (__bf16)v1.y, (__bf16)v1.z, (__bf16)v1.w};
        } else {
            a = *(const bf16x8*)((const unsigned short*)Asrc + (size_t)arow * 128 + kb);
        }
#pragma unroll
        for (int nt = 0; nt < 8; ++nt) {
            bf16x8 b = *(const bf16x8*)&sBT[(nt * 16 + lrow) * PAD_K + kb];
            acc[nt] = __builtin_amdgcn_mfma_f32_16x16x32_bf16(a, b, acc[nt], 0, 0, 0);
        }
    }

    // store: row = rbase + 16*wave + 4*quad + r, col = 16*nt + lrow
#pragma unroll
    for (int r = 0; r < 4; ++r) {
        int grow = rbase + wave * 16 + quad * 4 + r;
        if (grow < n) {
            float dsc = SCALE ? dinv[grow] : 1.0f;
            unsigned short* orow = outb + (size_t)grow * NDIM + lrow;
#pragma unroll
            for (int nt = 0; nt < 8; ++nt)
                orow[nt * 16] = f2bf(SCALE ? dsc * acc[nt][r] : acc[nt][r]);
        }
    }
}

// ---------------- layer-1 aggregation: 16 lanes/row, gathers from 12.8MB embW1 table ----
__global__ void aggregate1(const unsigned short* __restrict__ tab, const int* __restrict__ x,
                           const int* __restrict__ rp, const int2* __restrict__ ew,
                           const float* __restrict__ dinv, const float* __restrict__ bias,
                           unsigned short* __restrict__ outb, int n) {
    int t = blockIdx.x * blockDim.x + threadIdx.x;
    int i = t >> 4, u = t & 15;
    if (i >= n) return;
    const uint4* tab4 = (const uint4*)tab;  // row = 16 x uint4
    float di = dinv[i];
    float acc[8];
    {
        float f[8];
        unpack8(tab4[(size_t)x[i] * 16 + u], f);  // self term: di * embW1[x_i]
#pragma unroll
        for (int k = 0; k < 8; ++k) acc[k] = di * f[k];
    }
    int j = (i == 0) ? 0 : rp[i - 1];
    const int end = rp[i];
    for (; j + 4 <= end; j += 4) {
        int2 e0 = ew[j], e1 = ew[j + 1], e2 = ew[j + 2], e3 = ew[j + 3];
        uint4 q0 = tab4[(size_t)e0.x * 16 + u];
        uint4 q1 = tab4[(size_t)e1.x * 16 + u];
        uint4 q2 = tab4[(size_t)e2.x * 16 + u];
        uint4 q3 = tab4[(size_t)e3.x * 16 + u];
        float f0[8], f1[8], f2[8], f3[8];
        unpack8(q0, f0); unpack8(q1, f1); unpack8(q2, f2); unpack8(q3, f3);
        float n0 = __int_as_float(e0.y), n1 = __int_as_float(e1.y);
        float n2 = __int_as_float(e2.y), n3 = __int_as_float(e3.y);
#pragma unroll
        for (int k = 0; k < 8; ++k) {
            float s01 = fmaf(n0, f0[k], n1 * f1[k]);
            float s23 = fmaf(n2, f2[k], n3 * f3[k]);
            acc[k] += s01 + s23;
        }
    }
    for (; j < end; ++j) {
        int2 e = ew[j];
        uint4 q = tab4[(size_t)e.x * 16 + u];
        float f[8];
        unpack8(q, f);
        float nm = __int_as_float(e.y);
#pragma unroll
        for (int k = 0; k < 8; ++k) acc[k] = fmaf(nm, f[k], acc[k]);
    }
    const float4 b0 = ((const float4*)bias)[u * 2];
    const float4 b1 = ((const float4*)bias)[u * 2 + 1];
    float r[8];
    r[0] = fmaxf(fmaf(di, acc[0], b0.x), 0.0f);
    r[1] = fmaxf(fmaf(di, acc[1], b0.y), 0.0f);
    r[2] = fmaxf(fmaf(di, acc[2], b0.z), 0.0f);
    r[3] = fmaxf(fmaf(di, acc[3], b0.w), 0.0f);
    r[4] = fmaxf(fmaf(di, acc[4], b1.x), 0.0f);
    r[5] = fmaxf(fmaf(di, acc[5], b1.y), 0.0f);
    r[6] = fmaxf(fmaf(di, acc[6], b1.z), 0.0f);
    r[7] = fmaxf(fmaf(di, acc[7], b1.w), 0.0f);
    uint4 o;
    o.x = (unsigned)f2bf(r[0]) | ((unsigned)f2bf(r[1]) << 16);
    o.y = (unsigned)f2bf(r[2]) | ((unsigned)f2bf(r[3]) << 16);
    o.z = (unsigned)f2bf(r[4]) | ((unsigned)f2bf(r[5]) << 16);
    o.w = (unsigned)f2bf(r[6]) | ((unsigned)f2bf(r[7]) << 16);
    ((uint4*)outb)[(size_t)i * 16 + u] = o;
}

// ---------------- layer-2 aggregation: vs2 rows pre-scaled, fp32 output ----------------
__global__ void aggregate2(const unsigned short* __restrict__ vs, const int* __restrict__ rp,
                           const int* __restrict__ esrc, const float* __restrict__ dinv,
                           const float* __restrict__ bias, float* __restrict__ out, int n) {
    int t = blockIdx.x * blockDim.x + threadIdx.x;
    int i = t >> 4, u = t & 15;
    if (i >= n) return;
    const uint4* vs4 = (const uint4*)vs;
    float acc[8];
    unpack8(vs4[(size_t)i * 16 + u], acc);  // self term (already di-scaled)
    int j = (i == 0) ? 0 : rp[i - 1];
    const int end = rp[i];
    for (; j + 4 <= end; j += 4) {
        int s0 = esrc[j], s1 = esrc[j + 1], s2 = esrc[j + 2], s3 = esrc[j + 3];
        uint4 q0 = vs4[(size_t)s0 * 16 + u];
        uint4 q1 = vs4[(size_t)s1 * 16 + u];
        uint4 q2 = vs4[(size_t)s2 * 16 + u];
        uint4 q3 = vs4[(size_t)s3 * 16 + u];
        float f0[8], f1[8], f2[8], f3[8];
        unpack8(q0, f0); unpack8(q1, f1); unpack8(q2, f2); unpack8(q3, f3);
#pragma unroll
        for (int k = 0; k < 8; ++k) acc[k] += (f0[k] + f1[k]) + (f2[k] + f3[k]);
    }
    for (; j < end; ++j) {
        int s = esrc[j];
        uint4 q = vs4[(size_t)s * 16 + u];
        float f[8];
        unpack8(q, f);
#pragma unroll
        for (int k = 0; k < 8; ++k) acc[k] += f[k];
    }
    float di = dinv[i];
    const float4 b0 = ((const float4*)bias)[u * 2];
    const float4 b1 = ((const float4*)bias)[u * 2 + 1];
    float4 r0, r1;
    r0.x = fmaxf(fmaf(di, acc[0], b0.x), 0.0f);
    r0.y = fmaxf(fmaf(di, acc[1], b0.y), 0.0f);
    r0.z = fmaxf(fmaf(di, acc[2], b0.z), 0.0f);
    r0.w = fmaxf(fmaf(di, acc[3], b0.w), 0.0f);
    r1.x = fmaxf(fmaf(di, acc[4], b1.x), 0.0f);
    r1.y = fmaxf(fmaf(di, acc[5], b1.y), 0.0f);
    r1.z = fmaxf(fmaf(di, acc[6], b1.z), 0.0f);
    r1.w = fmaxf(fmaf(di, acc[7], b1.w), 0.0f);
    ((float4*)out)[(size_t)i * 32 + u * 2] = r0;
    ((float4*)out)[(size_t)i * 32 + u * 2 + 1] = r1;
}

extern "C" void kernel_launch(void* const* d_in, const int* in_sizes, int n_in,
                              void* d_out, int out_size, void* d_ws, size_t ws_size,
                              hipStream_t stream) {
    const int* x = (const int*)d_in[0];
    const int* edge_index = (const int*)d_in[1];
    const float* emb = (const float*)d_in[2];
    const float* W1 = (const float*)d_in[3];
    const float* b1 = (const float*)d_in[4];
    const float* W2 = (const float*)d_in[5];
    const float* b2 = (const float*)d_in[6];
    float* out = (float*)d_out;

    const int N = in_sizes[0];
    const int E = in_sizes[1] / 2;
    const int V = in_sizes[2] / NDIM;  // vocab rows
    const int* src = edge_index;
    const int* dst = edge_index + E;

    char* p = (char*)d_ws;
    auto alloc = [&](size_t bytes) {
        char* q = p;
        p += (bytes + 511) & ~(size_t)511;
        return q;
    };
    int* cnt = (int*)alloc((size_t)N * sizeof(int));
    int* rp = (int*)alloc((size_t)N * sizeof(int));
    float* dinv = (float*)alloc((size_t)N * sizeof(float));
    int* bsums = (int*)alloc(128 * sizeof(int));
    int* esrc = (int*)alloc((size_t)E * sizeof(int));
    int2* ew = (int2*)alloc((size_t)E * sizeof(int2));
    unsigned short* WT1 = (unsigned short*)alloc(16384 * sizeof(unsigned short));
    unsigned short* WT2 = (unsigned short*)alloc(16384 * sizeof(unsigned short));
    unsigned short* embW1 = (unsigned short*)alloc((size_t)V * NDIM * sizeof(unsigned short));
    unsigned short* h1b = (unsigned short*)alloc((size_t)N * NDIM * sizeof(unsigned short));
    unsigned short* vs2 = (unsigned short*)alloc((size_t)N * NDIM * sizeof(unsigned short));
    (void)ws_size;

    const int NB = (N + SCAN_IPB - 1) / SCAN_IPB;  // 98 <= 128

    // CSR build + dinv (rp becomes inclusive scan after fill_edges)
    hipMemsetAsync(cnt, 0, (size_t)N * sizeof(int), stream);
    degree_count<<<(E + 255) / 256, 256, 0, stream>>>(dst, cnt, E);
    scan_blocks<<<NB, SCAN_BLK, 0, stream>>>(cnt, rp, bsums, N);
    scan_partials<<<1, 128, 0, stream>>>(bsums, NB);
    add_offsets_dinv<<<(N + 255) / 256, 256, 0, stream>>>(rp, bsums, cnt, dinv, N);
    fill_edges<<<(E + 255) / 256, 256, 0, stream>>>(src, dst, rp, x, dinv, esrc, ew, E);

    // weights -> bf16 transposed
    wt_convert2<<<128, 256, 0, stream>>>(W1, W2, WT1, WT2);

    const int agg_blocks = (int)(((size_t)N * 16 + 255) / 256);

    // layer 1: vocab-table GEMM, then fused gather-aggregate
    gemm_mfma<0, false><<<(V + 63) / 64, 256, 0, stream>>>(emb, WT1, nullptr, embW1, V);
    aggregate1<<<agg_blocks, 256, 0, stream>>>(embW1, x, rp, ew, dinv, b1, h1b, N);
    // layer 2
    gemm_mfma<1, true><<<(N + 63) / 64, 256, 0, stream>>>(h1b, WT2, dinv, vs2, N);
    aggregate2<<<agg_blocks, 256, 0, stream>>>(vs2, rp, esrc, dinv, b2, out, N);
}

// Round 7
// 242.171 us; speedup vs baseline: 9.5802x; 1.0216x over previous
//
#include <hip/hip_runtime.h>

// GCN 2-layer, bf16-MFMA GEMM + CSR atomic-free aggregation.
// h1 = relu(Anorm @ (emb[x] @ W1) + b1); out = relu(Anorm @ (h1 @ W2) + b2)
// Anorm = D^-1/2 (A+I) D^-1/2.
// (emb[x]) @ W1 == (emb @ W1)[x]: layer-1 GEMM runs over the 50k-row vocab table.
// Per-edge payload ew[p] = int4(src, x[src], bits(dinv[src]), 0) written with ONE
// 16B scatter per edge (write-amplification is per-cacheline, so fewer scatters win).
//   layer1: out_i = relu(di*(sum_e dinv_e * embW1[ew.y] + di*embW1[x_i]) + b1)
//   layer2: rows pre-scaled by dinv in GEMM epilogue (vs2); edge loop adds vs2[ew.x].

#define NDIM 128
#define PAD_K 136  // LDS k-stride for B^T (+8 elems = 16B pad)
#define SCAN_IPT 4
#define SCAN_BLK 256
#define SCAN_IPB (SCAN_BLK * SCAN_IPT)

typedef __bf16 bf16x8 __attribute__((ext_vector_type(8)));
typedef float f32x4 __attribute__((ext_vector_type(4)));

__device__ __forceinline__ float bf2f(unsigned short u) {
    union { unsigned int i; float f; } c;
    c.i = (unsigned int)u << 16;
    return c.f;
}
__device__ __forceinline__ unsigned short f2bf(float f) {
    __bf16 b = (__bf16)f;
    return __builtin_bit_cast(unsigned short, b);
}
__device__ __forceinline__ void unpack8(uint4 q, float* f) {
    f[0] = bf2f((unsigned short)(q.x & 0xffff));
    f[1] = bf2f((unsigned short)(q.x >> 16));
    f[2] = bf2f((unsigned short)(q.y & 0xffff));
    f[3] = bf2f((unsigned short)(q.y >> 16));
    f[4] = bf2f((unsigned short)(q.z & 0xffff));
    f[5] = bf2f((unsigned short)(q.z >> 16));
    f[6] = bf2f((unsigned short)(q.w & 0xffff));
    f[7] = bf2f((unsigned short)(q.w >> 16));
}

// ---------------- CSR build ----------------
__global__ void degree_count(const int* __restrict__ dst, int* __restrict__ cnt, int E) {
    int e = blockIdx.x * blockDim.x + threadIdx.x;
    if (e < E) atomicAdd(&cnt[dst[e]], 1);
}

__global__ void scan_blocks(const int* __restrict__ in, int* __restrict__ out,
                            int* __restrict__ bsums, int n) {
    __shared__ int lds[SCAN_BLK];
    const int t = threadIdx.x;
    const int base = blockIdx.x * SCAN_IPB + t * SCAN_IPT;
    int v[SCAN_IPT];
    int s = 0;
#pragma unroll
    for (int k = 0; k < SCAN_IPT; ++k) { v[k] = (base + k < n) ? in[base + k] : 0; s += v[k]; }
    lds[t] = s;
    __syncthreads();
    for (int off = 1; off < SCAN_BLK; off <<= 1) {
        int x = (t >= off) ? lds[t - off] : 0;
        __syncthreads();
        lds[t] += x;
        __syncthreads();
    }
    if (t == SCAN_BLK - 1) bsums[blockIdx.x] = lds[t];
    int run = (t == 0) ? 0 : lds[t - 1];
#pragma unroll
    for (int k = 0; k < SCAN_IPT; ++k) {
        if (base + k < n) out[base + k] = run;
        run += v[k];
    }
}

__global__ void scan_partials(int* __restrict__ bsums, int nb) {
    __shared__ int lds[128];
    const int t = threadIdx.x;
    lds[t] = (t < nb) ? bsums[t] : 0;
    __syncthreads();
    for (int off = 1; off < 128; off <<= 1) {
        int x = (t >= off) ? lds[t - off] : 0;
        __syncthreads();
        lds[t] += x;
        __syncthreads();
    }
    if (t < nb) bsums[t] = (t == 0) ? 0 : lds[t - 1];
}

// blocks [0, nblkA): rp[i]+=bsums, dinv=rsqrt(cnt+1).  blocks [nblkA, ...): W^T bf16 convert.
__global__ void add_offsets_dinv_wt(int* __restrict__ rp, const int* __restrict__ bsums,
                                    const int* __restrict__ cnt, float* __restrict__ dinv, int n,
                                    int nblkA,
                                    const float* __restrict__ W1, const float* __restrict__ W2,
                                    unsigned short* __restrict__ WT1,
                                    unsigned short* __restrict__ WT2) {
    if ((int)blockIdx.x < nblkA) {
        int i = blockIdx.x * blockDim.x + threadIdx.x;
        if (i < n) {
            rp[i] += bsums[i / SCAN_IPB];
            dinv[i] = rsqrtf((float)cnt[i] + 1.0f);  // +1 self-loop
        }
    } else {
        int c = (blockIdx.x - nblkA) * blockDim.x + threadIdx.x;  // 0..32767
        int cc = c & 16383;
        int j = cc >> 7, k = cc & 127;
        if (c < 16384) WT1[cc] = f2bf(W1[k * 128 + j]);
        else if (c < 32768) WT2[cc] = f2bf(W2[k * 128 + j]);
    }
}

// Increments rp[d] in place: afterwards rp[i] == inclusive scan, so row i's edge
// range is [i==0 ? 0 : rp[i-1], rp[i]).  One 16B scatter per edge; 2 edges/thread.
__global__ void fill_edges(const int* __restrict__ src, const int* __restrict__ dst,
                           int* __restrict__ rp, const int* __restrict__ x,
                           const float* __restrict__ dinv, int4* __restrict__ ew, int E) {
    const int stride = gridDim.x * blockDim.x;
    int e = blockIdx.x * blockDim.x + threadIdx.x;
#pragma unroll
    for (int k = 0; k < 2; ++k, e += stride) {
        if (e < E) {
            int d = dst[e], s = src[e];
            int xs = x[s];
            float ds = dinv[s];
            int p = atomicAdd(&rp[d], 1);
            ew[p] = make_int4(s, xs, __float_as_int(ds), 0);
        }
    }
}

// ---------------- bf16 MFMA GEMM: outb[r][:] = (dinv[r]?) * (A[r][:] @ W) ----------------
// MODE 0: A rows fp32 (sequential, convert inline).  MODE 1: A rows bf16.
// Block: 256 threads (4 waves), tile 64 rows x 128 cols; wave w rows [16w,16w+16).
// A fragments read DIRECTLY from global (16B/lane contiguous, exactly-once traffic);
// only B^T staged in LDS (34 KB -> 4 blocks/CU).  mfma_f32_16x16x32_bf16:
// A-frag A[m=lane&15][k=quad*8+j]; B-frag B[k][n=lane&15] (B^T staged [n][k]);
// C/D: col=lane&15, row=quad*4+reg.
template <int MODE, bool SCALE>
__global__ __launch_bounds__(256, 4)
void gemm_mfma(const void* __restrict__ Asrc, const unsigned short* __restrict__ WTb,
               const float* __restrict__ dinv, unsigned short* __restrict__ outb, int n) {
    __shared__ __bf16 sBT[128 * PAD_K];
    const int tid = threadIdx.x;
    const int rbase = blockIdx.x * 64;

    {
        const uint4* bsrc = (const uint4*)WTb;
#pragma unroll
        for (int i = 0; i < 8; ++i) {
            int c = tid + i * 256;          // 2048 x 16B
            int j = c >> 4, u = c & 15;
            *(uint4*)&sBT[j * PAD_K + u * 8] = bsrc[c];
        }
    }
    __syncthreads();

    const int wave = tid >> 6, lane = tid & 63;
    const int quad = lane >> 4, lrow = lane & 15;
    int arow = rbase + wave * 16 + lrow;
    if (arow >= n) arow = n - 1;  // clamp; guarded at store

    f32x4 acc[8];
#pragma unroll
    for (int nt = 0; nt < 8; ++nt) acc[nt] = (f32x4)0.0f;

#pragma unroll
    for (int ks = 0; ks < 4; ++ks) {
        const int kb = ks * 32 + quad * 8;
        bf16x8 a;
        if (MODE == 0) {
            const float4* A4 = (const float4*)Asrc;
            float4 v0 = A4[(size_t)arow * 32 + (kb >> 2)];
            float4 v1 = A4[(size_t)arow * 32 + (kb >> 2) + 1];
            a = (bf16x8){(__bf16)v0.x, (__bf16)v0.y, (__bf16)v0.z, (__bf16)v0.w,
                         (__bf16)v1.x, (__bf16)v1.y, (__bf16)v1.z, (__bf16)v1.w};
        } else {
            a = *(const bf16x8*)((const unsigned short*)Asrc + (size_t)arow * 128 + kb);
        }
#pragma unroll
        for (int nt = 0; nt < 8; ++nt) {
            bf16x8 b = *(const bf16x8*)&sBT[(nt * 16 + lrow) * PAD_K + kb];
            acc[nt] = __builtin_amdgcn_mfma_f32_16x16x32_bf16(a, b, acc[nt], 0, 0, 0);
        }
    }

    // store: row = rbase + 16*wave + 4*quad + r, col = 16*nt + lrow
#pragma unroll
    for (int r = 0; r < 4; ++r) {
        int grow = rbase + wave * 16 + quad * 4 + r;
        if (grow < n) {
            float dsc = SCALE ? dinv[grow] : 1.0f;
            unsigned short* orow = outb + (size_t)grow * NDIM + lrow;
#pragma unroll
            for (int nt = 0; nt < 8; ++nt)
                orow[nt * 16] = f2bf(SCALE ? dsc * acc[nt][r] : acc[nt][r]);
        }
    }
}

// ---------------- layer-1 aggregation: 16 lanes/row, gathers from 12.8MB embW1 table ----
__global__ void aggregate1(const unsigned short* __restrict__ tab, const int* __restrict__ x,
                           const int* __restrict__ rp, const int4* __restrict__ ew,
                           const float* __restrict__ dinv, const float* __restrict__ bias,
                           unsigned short* __restrict__ outb, int n) {
    int t = blockIdx.x * blockDim.x + threadIdx.x;
    int i = t >> 4, u = t & 15;
    if (i >= n) return;
    const uint4* tab4 = (const uint4*)tab;  // row = 16 x uint4
    float di = dinv[i];
    float acc[8];
    {
        float f[8];
        unpack8(tab4[(size_t)x[i] * 16 + u], f);  // self term: di * embW1[x_i]
#pragma unroll
        for (int k = 0; k < 8; ++k) acc[k] = di * f[k];
    }
    int j = (i == 0) ? 0 : rp[i - 1];
    const int end = rp[i];
    for (; j + 4 <= end; j += 4) {
        int4 e0 = ew[j], e1 = ew[j + 1], e2 = ew[j + 2], e3 = ew[j + 3];
        uint4 q0 = tab4[(size_t)e0.y * 16 + u];
        uint4 q1 = tab4[(size_t)e1.y * 16 + u];
        uint4 q2 = tab4[(size_t)e2.y * 16 + u];
        uint4 q3 = tab4[(size_t)e3.y * 16 + u];
        float f0[8], f1[8], f2[8], f3[8];
        unpack8(q0, f0); unpack8(q1, f1); unpack8(q2, f2); unpack8(q3, f3);
        float n0 = __int_as_float(e0.z), n1 = __int_as_float(e1.z);
        float n2 = __int_as_float(e2.z), n3 = __int_as_float(e3.z);
#pragma unroll
        for (int k = 0; k < 8; ++k) {
            float s01 = fmaf(n0, f0[k], n1 * f1[k]);
            float s23 = fmaf(n2, f2[k], n3 * f3[k]);
            acc[k] += s01 + s23;
        }
    }
    for (; j < end; ++j) {
        int4 e = ew[j];
        uint4 q = tab4[(size_t)e.y * 16 + u];
        float f[8];
        unpack8(q, f);
        float nm = __int_as_float(e.z);
#pragma unroll
        for (int k = 0; k < 8; ++k) acc[k] = fmaf(nm, f[k], acc[k]);
    }
    const float4 b0 = ((const float4*)bias)[u * 2];
    const float4 b1 = ((const float4*)bias)[u * 2 + 1];
    float r[8];
    r[0] = fmaxf(fmaf(di, acc[0], b0.x), 0.0f);
    r[1] = fmaxf(fmaf(di, acc[1], b0.y), 0.0f);
    r[2] = fmaxf(fmaf(di, acc[2], b0.z), 0.0f);
    r[3] = fmaxf(fmaf(di, acc[3], b0.w), 0.0f);
    r[4] = fmaxf(fmaf(di, acc[4], b1.x), 0.0f);
    r[5] = fmaxf(fmaf(di, acc[5], b1.y), 0.0f);
    r[6] = fmaxf(fmaf(di, acc[6], b1.z), 0.0f);
    r[7] = fmaxf(fmaf(di, acc[7], b1.w), 0.0f);
    uint4 o;
    o.x = (unsigned)f2bf(r[0]) | ((unsigned)f2bf(r[1]) << 16);
    o.y = (unsigned)f2bf(r[2]) | ((unsigned)f2bf(r[3]) << 16);
    o.z = (unsigned)f2bf(r[4]) | ((unsigned)f2bf(r[5]) << 16);
    o.w = (unsigned)f2bf(r[6]) | ((unsigned)f2bf(r[7]) << 16);
    ((uint4*)outb)[(size_t)i * 16 + u] = o;
}

// ---------------- layer-2 aggregation: vs2 rows pre-scaled, fp32 output ----------------
__global__ void aggregate2(const unsigned short* __restrict__ vs, const int* __restrict__ rp,
                           const int4* __restrict__ ew, const float* __restrict__ dinv,
                           const float* __restrict__ bias, float* __restrict__ out, int n) {
    int t = blockIdx.x * blockDim.x + threadIdx.x;
    int i = t >> 4, u = t & 15;
    if (i >= n) return;
    const uint4* vs4 = (const uint4*)vs;
    float acc[8];
    unpack8(vs4[(size_t)i * 16 + u], acc);  // self term (already di-scaled)
    int j = (i == 0) ? 0 : rp[i - 1];
    const int end = rp[i];
    for (; j + 4 <= end; j += 4) {
        int s0 = ew[j].x, s1 = ew[j + 1].x, s2 = ew[j + 2].x, s3 = ew[j + 3].x;
        uint4 q0 = vs4[(size_t)s0 * 16 + u];
        uint4 q1 = vs4[(size_t)s1 * 16 + u];
        uint4 q2 = vs4[(size_t)s2 * 16 + u];
        uint4 q3 = vs4[(size_t)s3 * 16 + u];
        float f0[8], f1[8], f2[8], f3[8];
        unpack8(q0, f0); unpack8(q1, f1); unpack8(q2, f2); unpack8(q3, f3);
#pragma unroll
        for (int k = 0; k < 8; ++k) acc[k] += (f0[k] + f1[k]) + (f2[k] + f3[k]);
    }
    for (; j < end; ++j) {
        int s = ew[j].x;
        uint4 q = vs4[(size_t)s * 16 + u];
        float f[8];
        unpack8(q, f);
#pragma unroll
        for (int k = 0; k < 8; ++k) acc[k] += f[k];
    }
    float di = dinv[i];
    const float4 b0 = ((const float4*)bias)[u * 2];
    const float4 b1 = ((const float4*)bias)[u * 2 + 1];
    float4 r0, r1;
    r0.x = fmaxf(fmaf(di, acc[0], b0.x), 0.0f);
    r0.y = fmaxf(fmaf(di, acc[1], b0.y), 0.0f);
    r0.z = fmaxf(fmaf(di, acc[2], b0.z), 0.0f);
    r0.w = fmaxf(fmaf(di, acc[3], b0.w), 0.0f);
    r1.x = fmaxf(fmaf(di, acc[4], b1.x), 0.0f);
    r1.y = fmaxf(fmaf(di, acc[5], b1.y), 0.0f);
    r1.z = fmaxf(fmaf(di, acc[6], b1.z), 0.0f);
    r1.w = fmaxf(fmaf(di, acc[7], b1.w), 0.0f);
    ((float4*)out)[(size_t)i * 32 + u * 2] = r0;
    ((float4*)out)[(size_t)i * 32 + u * 2 + 1] = r1;
}

extern "C" void kernel_launch(void* const* d_in, const int* in_sizes, int n_in,
                              void* d_out, int out_size, void* d_ws, size_t ws_size,
                              hipStream_t stream) {
    const int* x = (const int*)d_in[0];
    const int* edge_index = (const int*)d_in[1];
    const float* emb = (const float*)d_in[2];
    const float* W1 = (const float*)d_in[3];
    const float* b1 = (const float*)d_in[4];
    const float* W2 = (const float*)d_in[5];
    const float* b2 = (const float*)d_in[6];
    float* out = (float*)d_out;

    const int N = in_sizes[0];
    const int E = in_sizes[1] / 2;
    const int V = in_sizes[2] / NDIM;  // vocab rows
    const int* src = edge_index;
    const int* dst = edge_index + E;

    char* p = (char*)d_ws;
    auto alloc = [&](size_t bytes) {
        char* q = p;
        p += (bytes + 511) & ~(size_t)511;
        return q;
    };
    int* cnt = (int*)alloc((size_t)N * sizeof(int));
    int* rp = (int*)alloc((size_t)N * sizeof(int));
    float* dinv = (float*)alloc((size_t)N * sizeof(float));
    int* bsums = (int*)alloc(128 * sizeof(int));
    int4* ew = (int4*)alloc((size_t)E * sizeof(int4));
    unsigned short* WT1 = (unsigned short*)alloc(16384 * sizeof(unsigned short));
    unsigned short* WT2 = (unsigned short*)alloc(16384 * sizeof(unsigned short));
    unsigned short* embW1 = (unsigned short*)alloc((size_t)V * NDIM * sizeof(unsigned short));
    unsigned short* h1b = (unsigned short*)alloc((size_t)N * NDIM * sizeof(unsigned short));
    unsigned short* vs2 = (unsigned short*)alloc((size_t)N * NDIM * sizeof(unsigned short));
    (void)ws_size;

    const int NB = (N + SCAN_IPB - 1) / SCAN_IPB;  // 98 <= 128
    const int nblkA = (N + 255) / 256;

    // CSR build + dinv (rp becomes inclusive scan after fill_edges)
    hipMemsetAsync(cnt, 0, (size_t)N * sizeof(int), stream);
    degree_count<<<(E + 255) / 256, 256, 0, stream>>>(dst, cnt, E);
    scan_blocks<<<NB, SCAN_BLK, 0, stream>>>(cnt, rp, bsums, N);
    scan_partials<<<1, 128, 0, stream>>>(bsums, NB);
    add_offsets_dinv_wt<<<nblkA + 128, 256, 0, stream>>>(rp, bsums, cnt, dinv, N, nblkA,
                                                         W1, W2, WT1, WT2);
    fill_edges<<<(E / 2 + 255) / 256, 256, 0, stream>>>(src, dst, rp, x, dinv, ew, E);

    const int agg_blocks = (int)(((size_t)N * 16 + 255) / 256);

    // layer 1: vocab-table GEMM, then fused gather-aggregate
    gemm_mfma<0, false><<<(V + 63) / 64, 256, 0, stream>>>(emb, WT1, nullptr, embW1, V);
    aggregate1<<<agg_blocks, 256, 0, stream>>>(embW1, x, rp, ew, dinv, b1, h1b, N);
    // layer 2
    gemm_mfma<1, true><<<(N + 63) / 64, 256, 0, stream>>>(h1b, WT2, dinv, vs2, N);
    aggregate2<<<agg_blocks, 256, 0, stream>>>(vs2, rp, ew, dinv, b2, out, N);
}